// Round 11
// baseline (188.252 us; speedup 1.0000x reference)
//
#include <hip/hip_runtime.h>
#include <math.h>

typedef unsigned short u16;
typedef __attribute__((ext_vector_type(8))) short short8;
typedef __attribute__((ext_vector_type(4))) float floatx4;

__device__ __forceinline__ float b2f(u16 u) { return __uint_as_float(((unsigned)u) << 16); }
__device__ __forceinline__ u16 f2b(float f) {
  unsigned u = __float_as_uint(f);
  return (u16)((u + 0x7fffu + ((u >> 16) & 1u)) >> 16);
}

// ---------- fused prep: cast x -> bf16 | cast 4 weights | build Wcat ----------
// W0/W1/W2 are emitted in MFMA-fragment-major layout: per (ntile16, kchunk32) a 1KB
// block ordered lane*8+e. A wave's B-fragment load is then ONE contiguous 1KB burst,
// and the layout is lane-linear so global_load_lds (dest = base + lane*16) maps 1:1.
__global__ __launch_bounds__(256) void prep_cast(const float* __restrict__ x, const float* __restrict__ wpr,
                                                 const float* __restrict__ w0, const float* __restrict__ w1,
                                                 const float* __restrict__ w2, const float* __restrict__ qp,
                                                 const float* __restrict__ kp, const float* __restrict__ wv,
                                                 u16* __restrict__ XB, u16* __restrict__ WPRb,
                                                 u16* __restrict__ W0b, u16* __restrict__ W1b,
                                                 u16* __restrict__ W2b, u16* __restrict__ wcat) {
  int bi = blockIdx.x, tid = threadIdx.x;
  if (bi < 2048) {                       // cast_x: 524288 float4s
    int i = bi * 256 + tid;
    float4 v = ((const float4*)x)[i];
    ushort4 o; o.x = f2b(v.x); o.y = f2b(v.y); o.z = f2b(v.z); o.w = f2b(v.w);
    ((ushort4*)XB)[i] = o;
  } else if (bi < 3072) {                // cast 4x 512x512 weights: 262144 float4s
    int i = (bi - 2048) * 256 + tid;
    int sel = i >> 16, j = i & 65535;
    const float* s = sel == 0 ? wpr : sel == 1 ? w0 : sel == 2 ? w1 : w2;
    float4 v = ((const float4*)s)[j];
    ushort4 o; o.x = f2b(v.x); o.y = f2b(v.y); o.z = f2b(v.z); o.w = f2b(v.w);
    if (sel == 0) {
      ((ushort4*)WPRb)[j] = o;           // row-major (mgemm path)
    } else {                             // fragment-major scatter (enc_fused path)
      u16* d = sel == 1 ? W0b : sel == 2 ? W1b : W2b;
      int n = j >> 7, k4 = (j & 127) << 2;        // n row, k col (aligned 4)
      int lane = (((k4 >> 3) & 3) << 4) | (n & 15);
      int dst = (((n >> 4) * 16 + (k4 >> 5)) << 9) + lane * 8 + (k4 & 7);
      *(ushort4*)(d + dst) = o;
    }
  } else {                               // build_wcat: 524288 elements
    int i = (bi - 3072) * 256 + tid;
    int d = i & 511, c = i >> 9;
    float v;
    if (c < 512) {
      int hh = c >> 5, o = c & 31;
      const float* src = (hh < 8) ? qp : kp;
      int h = hh & 7;
      v = src[(h * 512 + d) * 32 + o];
    } else {
      v = wv[(c - 512) * 512 + d];
    }
    wcat[i] = f2b(v);
  }
}

// ---------- bf16 MFMA GEMM v2 (verified 223us baseline): BK=64, register prefetch ----------
// C[M x N] = A[M x 512] @ B^T.  EPI: 0 plain, 1 +X, 2 X + silu(acc). DUAL: also store bf16.
template <int EPI, bool DUAL>
__global__ __launch_bounds__(256) void mgemm(const u16* __restrict__ A, const u16* __restrict__ Bw,
                                             const float* __restrict__ X, float* __restrict__ C,
                                             u16* __restrict__ Cb, int N) {
  __shared__ u16 As[64][72];  // stride 144B = 9*16 (b128-aligned), banks 2-way max
  __shared__ u16 Bs[64][72];
  const int tid = threadIdx.x;
  const int bm = blockIdx.y, bn = blockIdx.x;
  const int lane = tid & 63, wave = tid >> 6;
  const int wm = wave >> 1, wn = wave & 1;
  const int quad = lane >> 4, l16 = lane & 15;
  const int sr = tid >> 2;        // staging row 0..63
  const int sk = (tid & 3) << 4;  // k-chunk 0,16,32,48
  floatx4 acc[2][2] = {};
  const u16* Ap = A + (size_t)(bm * 64 + sr) * 512 + sk;
  const u16* Bp = Bw + (size_t)(bn * 64 + sr) * 512 + sk;
  uint4 a0 = *(const uint4*)(Ap);
  uint4 a1 = *(const uint4*)(Ap + 8);
  uint4 b0 = *(const uint4*)(Bp);
  uint4 b1 = *(const uint4*)(Bp + 8);
  for (int k0 = 0; k0 < 512; k0 += 64) {
    __syncthreads();
    *(uint4*)&As[sr][sk] = a0;
    *(uint4*)&As[sr][sk + 8] = a1;
    *(uint4*)&Bs[sr][sk] = b0;
    *(uint4*)&Bs[sr][sk + 8] = b1;
    __syncthreads();
    if (k0 + 64 < 512) {  // prefetch next tile; latency overlaps MFMAs below
      a0 = *(const uint4*)(Ap + k0 + 64);
      a1 = *(const uint4*)(Ap + k0 + 72);
      b0 = *(const uint4*)(Bp + k0 + 64);
      b1 = *(const uint4*)(Bp + k0 + 72);
    }
#pragma unroll
    for (int kk = 0; kk < 2; kk++) {
      short8 af0 = *(const short8*)&As[wm * 32 + l16][kk * 32 + quad * 8];
      short8 af1 = *(const short8*)&As[wm * 32 + 16 + l16][kk * 32 + quad * 8];
      short8 bf0 = *(const short8*)&Bs[wn * 32 + l16][kk * 32 + quad * 8];
      short8 bf1 = *(const short8*)&Bs[wn * 32 + 16 + l16][kk * 32 + quad * 8];
      acc[0][0] = __builtin_amdgcn_mfma_f32_16x16x32_bf16(af0, bf0, acc[0][0], 0, 0, 0);
      acc[0][1] = __builtin_amdgcn_mfma_f32_16x16x32_bf16(af0, bf1, acc[0][1], 0, 0, 0);
      acc[1][0] = __builtin_amdgcn_mfma_f32_16x16x32_bf16(af1, bf0, acc[1][0], 0, 0, 0);
      acc[1][1] = __builtin_amdgcn_mfma_f32_16x16x32_bf16(af1, bf1, acc[1][1], 0, 0, 0);
    }
  }
#pragma unroll
  for (int mt = 0; mt < 2; mt++)
#pragma unroll
    for (int r = 0; r < 4; r++) {
      int row = bm * 64 + wm * 32 + mt * 16 + quad * 4 + r;
#pragma unroll
      for (int nt = 0; nt < 2; nt++) {
        int col = bn * 64 + wn * 32 + nt * 16 + l16;
        float v = acc[mt][nt][r];
        if (EPI == 1) {
          v += X[(size_t)row * 512 + col];
        } else if (EPI == 2) {
          float xv = X[(size_t)row * 512 + col];
          v = xv + v / (1.f + __expf(-v));
        }
        C[(size_t)row * N + col] = v;
        if (DUAL) Cb[(size_t)row * N + col] = f2b(v);
      }
    }
}

// ---------- fused prep_attn: RoPE q,k -> bf16 (b,h,t,32) | V -> bf16 (b,h,64,T) ----------
// q-gain additionally folds log2(e) so attn_split can use v_exp_f32 (exp2) directly.
__global__ __launch_bounds__(256) void prep_attn(const float* __restrict__ qkv, const float* __restrict__ qgain,
                                                 u16* __restrict__ qr, u16* __restrict__ kr,
                                                 u16* __restrict__ Vt) {
  const int bi = blockIdx.x, tid = threadIdx.x;
  if (bi < 2048) {  // RoPE
    int gid = bi * 256 + tid;
    int o = gid & 15;
    int t = (gid >> 4) & 2047;
    int h = (gid >> 15) & 7;
    int b = gid >> 18;
    const float* row = qkv + (size_t)(b * 2048 + t) * 1024;
    float freq = powf(10000.f, -(float)o / 16.f);
    float ang = (float)t * freq;
    float s, c;
    sincosf(ang, &s, &c);
    // gain * 1/sqrt(32) * log2(e)  (exp2-based softmax downstream)
    float g = qgain[h] * (0.17677669529663687f * 1.4426950408889634f);
    int qb = h * 32;
    float q0 = row[qb + o], q1 = row[qb + o + 16];
    float k0 = row[256 + qb + o], k1 = row[256 + qb + o + 16];
    u16* qo = qr + ((size_t)((b * 8 + h) * 2048 + t)) * 32;
    u16* ko = kr + ((size_t)((b * 8 + h) * 2048 + t)) * 32;
    qo[o] = f2b((q0 * c - q1 * s) * g);
    qo[o + 16] = f2b((q1 * c + q0 * s) * g);
    ko[o] = f2b(k0 * c - k1 * s);
    ko[o + 16] = f2b(k1 * c + k0 * s);
  } else {  // V transpose
    int idx = bi - 2048;
    const int tt = idx & 31, bh = idx >> 5;
    const int b = bh >> 3, h = bh & 7;
    __shared__ u16 Ts[64][72];
    const int r = tid >> 2, q = tid & 3;
    const float* src = qkv + ((size_t)(b * 2048 + tt * 64 + r)) * 1024 + 512 + h * 64 + q * 16;
#pragma unroll
    for (int j = 0; j < 4; j++) {
      float4 v = *(const float4*)(src + j * 4);
      Ts[q * 16 + j * 4 + 0][r] = f2b(v.x);
      Ts[q * 16 + j * 4 + 1][r] = f2b(v.y);
      Ts[q * 16 + j * 4 + 2][r] = f2b(v.z);
      Ts[q * 16 + j * 4 + 3][r] = f2b(v.w);
    }
    __syncthreads();
    u16* dst = Vt + ((size_t)(bh * 64 + r)) * 2048 + tt * 64 + q * 16;
    *(uint4*)dst = *(const uint4*)&Ts[r][q * 16];
    *(uint4*)(dst + 8) = *(const uint4*)&Ts[r][q * 16 + 8];
  }
}

// ---------- MFMA causal attention, split-K (S=2), no-max softmax (exp2), K/V prefetch ----------
__global__ __launch_bounds__(256) void attn_split(const u16* __restrict__ Qb, const u16* __restrict__ Kb,
                                                  const u16* __restrict__ Vt, float* __restrict__ PO,
                                                  float* __restrict__ PL) {
  const int bi = blockIdx.x;               // 1024 blocks
  const int bh = bi & 15;
  const int q0i = (bi >> 4) & 15;
  const int rem = bi >> 8;                 // blocks j,j+256,j+512,j+768 share a CU:
  const int qt = (rem & 1) ? (31 - q0i) : q0i;  // per-CU work = const 33 iters
  const int s = rem >> 1;
  const int tid = threadIdx.x;
  const int w = tid >> 6, lane = tid & 63, quad = lane >> 4, l16 = lane & 15;
  __shared__ u16 Vts[64][72];
  __shared__ u16 Ps[4][16][72];

  const int mid = (qt + 1) >> 1;
  const int kt_beg = s ? mid : 0;
  const int kt_end = s ? (qt + 1) : mid;

  short8 qfrag = *(const short8*)(Qb + ((size_t)(bh * 2048 + qt * 64 + w * 16 + l16)) * 32 + quad * 8);
  floatx4 o_acc[4] = {};
  float l_part[4] = {0.f, 0.f, 0.f, 0.f};
  const u16* Kbase = Kb + (size_t)bh * 2048 * 32;
  const u16* Vtb = Vt + (size_t)bh * 64 * 2048;
  const int vr = tid >> 2, vc = (tid & 3) << 4;

  uint4 v0 = {}, v1 = {};
  short8 kf[4] = {};
  if (kt_beg < kt_end) {
    const u16* src = Vtb + (size_t)vr * 2048 + kt_beg * 64 + vc;
    v0 = *(const uint4*)src;
    v1 = *(const uint4*)(src + 8);
#pragma unroll
    for (int nt = 0; nt < 4; nt++)
      kf[nt] = *(const short8*)(Kbase + (size_t)(kt_beg * 64 + nt * 16 + l16) * 32 + quad * 8);
  }

  for (int kt = kt_beg; kt < kt_end; ++kt) {
    __syncthreads();
    *(uint4*)&Vts[vr][vc] = v0;
    *(uint4*)&Vts[vr][vc + 8] = v1;
    __syncthreads();
    const bool more = (kt + 1 < kt_end);
    uint4 v0n = {}, v1n = {};
    short8 kfn[4] = {};
    if (more) {  // prefetch next K/V; latency overlaps exp+MFMA below
      const u16* src = Vtb + (size_t)vr * 2048 + (kt + 1) * 64 + vc;
      v0n = *(const uint4*)src;
      v1n = *(const uint4*)(src + 8);
#pragma unroll
      for (int nt = 0; nt < 4; nt++)
        kfn[nt] = *(const short8*)(Kbase + (size_t)((kt + 1) * 64 + nt * 16 + l16) * 32 + quad * 8);
    }

    floatx4 s_acc[4];
#pragma unroll
    for (int nt = 0; nt < 4; nt++) {
      floatx4 zz = {0.f, 0.f, 0.f, 0.f};
      s_acc[nt] = __builtin_amdgcn_mfma_f32_16x16x32_bf16(qfrag, kf[nt], zz, 0, 0, 0);
    }
    const bool diag = (kt == qt);
#pragma unroll
    for (int r = 0; r < 4; r++) {
      int mloc = w * 16 + quad * 4 + r;
      float psum = 0.f;
#pragma unroll
      for (int nt = 0; nt < 4; nt++) {
        float p = __builtin_amdgcn_exp2f(s_acc[nt][r]);  // log2e folded into q-gain
        if (diag && (nt * 16 + l16) > mloc) p = 0.f;
        psum += p;
        Ps[w][quad * 4 + r][nt * 16 + l16] = f2b(p);
      }
      l_part[r] += psum;
    }
#pragma unroll
    for (int kc = 0; kc < 2; kc++) {
      short8 pf = *(const short8*)&Ps[w][l16][kc * 32 + quad * 8];
#pragma unroll
      for (int nt = 0; nt < 4; nt++) {
        short8 vf = *(const short8*)&Vts[nt * 16 + l16][kc * 32 + quad * 8];
        o_acc[nt] = __builtin_amdgcn_mfma_f32_16x16x32_bf16(pf, vf, o_acc[nt], 0, 0, 0);
      }
    }
    v0 = v0n; v1 = v1n;
#pragma unroll
    for (int nt = 0; nt < 4; nt++) kf[nt] = kfn[nt];
  }

  // store partials (unnormalized O, per-row l)
  const int pidx = (bh * 32 + qt) * 2 + s;
  float* pob = PO + (size_t)pidx * 4096;
#pragma unroll
  for (int r = 0; r < 4; r++) {
    float ls = l_part[r];
#pragma unroll
    for (int mk = 1; mk < 16; mk <<= 1) ls += __shfl_xor(ls, mk, 64);
    int row = w * 16 + quad * 4 + r;
#pragma unroll
    for (int nt = 0; nt < 4; nt++) pob[row * 64 + nt * 16 + l16] = o_acc[nt][r];
    if (l16 == 0) PL[pidx * 64 + row] = ls;
  }
}

// ---------- combine split-K partials + self-align + permute to (b,t,512) bf16 ----------
// grid must be 8192: 32768 (bh,tok) rows, 4 per block.
__global__ __launch_bounds__(256) void attn_combine(const float* __restrict__ PO, const float* __restrict__ PL,
                                                    const float* __restrict__ qkv, u16* __restrict__ y2b) {
  int ridx = blockIdx.x * 4 + (threadIdx.x >> 6);  // 0..32767
  int lane = threadIdx.x & 63;
  int bh = ridx >> 11, tok = ridx & 2047;
  int qt = tok >> 6, row = tok & 63;
  int pidx = (bh * 32 + qt) * 2;
  const float* p0 = PO + (size_t)pidx * 4096 + row * 64;
  float o = p0[lane] + p0[4096 + lane];
  float l = PL[pidx * 64 + row] + PL[(pidx + 1) * 64 + row];
  float yv = o / l;
  int b = bh >> 3, h = bh & 7;
  float vv = qkv[(size_t)(b * 2048 + tok) * 1024 + 512 + h * 64 + lane];
  float ss = vv * vv, dot = yv * vv;
#pragma unroll
  for (int mk = 1; mk < 64; mk <<= 1) {
    ss += __shfl_xor(ss, mk, 64);
    dot += __shfl_xor(dot, mk, 64);
  }
  float coef = dot / fmaxf(ss, 1e-24f);
  y2b[(size_t)(b * 2048 + tok) * 512 + h * 64 + lane] = f2b(yv - coef * vv);
}

// ---------- fused encoder: he0 -> ln1 -> he1 -> ln2 -> he2 -> rms -> proj -> z ----------
// v8 = v7 (r10, FAILED tripwire: WAR race) + sched_barrier(0) fences per guide rule #18.
// Root cause of the r10 race: hipcc may move register-only MFMAs (and the compiler's
// lgkmcnt for their ds_reads) across the "memory"-clobbered s_waitcnt asm -> the
// gload_lds restaging a buffer can issue before the prior ds_reads of that SAME
// buffer (2-buffer period) completed -> hardware WAR race -> nondeterministic output.
// Fix: __builtin_amdgcn_sched_barrier(0) after the stage-issue group (pins issue
// order so vmcnt counting is exact), after the waitcnt (reads can't hoist), and
// after the MFMA group (MFMAs + their lgkmcnt can't sink below the next stage issue,
// so buffer reads are COMPLETE before the aliasing buffer is overwritten).
#define HPAD 516  // hres row stride (floats)

__device__ __forceinline__ int enc_swz(int row, int col) {
  // u16 element index into [16][512]; XOR 16B-chunk swizzle kills the 1KB-stride bank conflict
  return row * 512 + ((((col >> 3) ^ (row & 7)) << 3) | (col & 7));
}

// Wst: [2][8 waves][4 nt][512 u16] = 64KB. Per-wave private double buffer.
__device__ __forceinline__ void enc_gemm(const u16* __restrict__ inb, const u16* __restrict__ Wf,
                                         u16* __restrict__ Wst, floatx4* acc,
                                         int wave, int lane, int l16, int quad, int krot) {
  const int wslot = wave * 4 * 512;
  const int lo = lane * 8;
  // prologue: stage p=0 (kc = krot) into buf0
#pragma unroll
  for (int nt = 0; nt < 4; nt++)
    __builtin_amdgcn_global_load_lds(
        (const __attribute__((address_space(1))) void*)(Wf + (((size_t)(wave * 4 + nt) * 16 + krot) << 9) + lo),
        (__attribute__((address_space(3))) void*)(Wst + wslot + nt * 512), 16, 0, 0);
  __builtin_amdgcn_sched_barrier(0);  // prologue's 4 are strictly oldest
#pragma unroll
  for (int p = 0; p < 16; p++) {
    if (p + 1 < 16) {  // issue async stage of p+1 into other buffer (4 x 1KB loads)
      const int kn = (p + 1 + krot) & 15;
      u16* bufN = Wst + ((p + 1) & 1) * (8 * 4 * 512) + wslot;
#pragma unroll
      for (int nt = 0; nt < 4; nt++)
        __builtin_amdgcn_global_load_lds(
            (const __attribute__((address_space(1))) void*)(Wf + (((size_t)(wave * 4 + nt) * 16 + kn) << 9) + lo),
            (__attribute__((address_space(3))) void*)(bufN + nt * 512), 16, 0, 0);
      __builtin_amdgcn_sched_barrier(0);  // pin issue order (vmcnt count exact)
      asm volatile("s_waitcnt vmcnt(4)" ::: "memory");  // oldest 4 (stage p) complete
    } else {
      asm volatile("s_waitcnt vmcnt(0)" ::: "memory");  // final stage complete
    }
    __builtin_amdgcn_sched_barrier(0);  // reads can't hoist above the wait
    const u16* bufC = Wst + (p & 1) * (8 * 4 * 512) + wslot;
    const int kc = (p + krot) & 15;
    short8 af = *(const short8*)(inb + enc_swz(l16, kc * 32 + quad * 8));
#pragma unroll
    for (int nt = 0; nt < 4; nt++) {
      short8 bf = *(const short8*)(bufC + nt * 512 + lo);
      acc[nt] = __builtin_amdgcn_mfma_f32_16x16x32_bf16(af, bf, acc[nt], 0, 0, 0);
    }
    __builtin_amdgcn_sched_barrier(0);  // MFMAs+lgkmcnt can't sink below next stage
  }
}

__global__ __launch_bounds__(512) void enc_fused(const float* __restrict__ H, const u16* __restrict__ W0b,
                                                 const u16* __restrict__ W1b, const u16* __restrict__ W2b,
                                                 const float* __restrict__ g1v, const float* __restrict__ b1v,
                                                 const float* __restrict__ g2v, const float* __restrict__ b2v,
                                                 const float* __restrict__ wout, const float* __restrict__ ct,
                                                 float* __restrict__ z) {
  __shared__ u16 curb[16 * 512];       // bf16 h (GEMM1 input), swizzled
  __shared__ u16 lnb[16 * 512];        // bf16 ln output (GEMM2/3 input), swizzled
  __shared__ u16 Wst[2 * 8 * 4 * 512]; // per-wave async weight staging (64KB)
  __shared__ float hres[16][HPAD];     // fp32 residual h -> he1 -> he2 (padded rows)
  __shared__ float red[8][16][2];      // per-wave per-row (sum, sumsq)

  const int tid = threadIdx.x;
  const int wave = tid >> 6, lane = tid & 63, quad = lane >> 4, l16 = lane & 15;
  const int row0 = blockIdx.x * 16;
  const int n0 = wave * 64;
  const int krot = (blockIdx.x >> 3) & 15;  // 16 distinct phases among each XCD's 32 blocks

  // ---- load h rows: fp32 -> hres, cast -> curb ----
#pragma unroll
  for (int j = 0; j < 4; j++) {
    int idx = j * 512 + tid;          // 2048 float4s
    int row = idx >> 7, c4 = idx & 127;
    float4 v = ((const float4*)H)[(size_t)(row0 + row) * 128 + c4];
    *(float4*)&hres[row][c4 * 4] = v;
    int col = c4 * 4;
    curb[enc_swz(row, col + 0)] = f2b(v.x);
    curb[enc_swz(row, col + 1)] = f2b(v.y);
    curb[enc_swz(row, col + 2)] = f2b(v.z);
    curb[enc_swz(row, col + 3)] = f2b(v.w);
  }
  __syncthreads();

  // ---- GEMM1: he0 = h @ w0^T ----
  floatx4 acc1[4] = {};
  enc_gemm(curb, W0b, Wst, acc1, wave, lane, l16, quad, krot);

  // ---- LN1 -> lnb (bf16) ----
  {
#pragma unroll
    for (int r = 0; r < 4; r++) {
      float s = 0.f, q = 0.f;
#pragma unroll
      for (int nt = 0; nt < 4; nt++) { float v = acc1[nt][r]; s += v; q = fmaf(v, v, q); }
#pragma unroll
      for (int mk = 1; mk < 16; mk <<= 1) { s += __shfl_xor(s, mk, 64); q += __shfl_xor(q, mk, 64); }
      if (l16 == 0) { red[wave][quad * 4 + r][0] = s; red[wave][quad * 4 + r][1] = q; }
    }
    __syncthreads();
#pragma unroll
    for (int r = 0; r < 4; r++) {
      int R = quad * 4 + r;
      float st = 0.f, qt2 = 0.f;
#pragma unroll
      for (int w2 = 0; w2 < 8; w2++) { st += red[w2][R][0]; qt2 += red[w2][R][1]; }
      float mean = st * (1.f / 512.f);
      float inv = rsqrtf(qt2 * (1.f / 512.f) - mean * mean + 1e-5f);
#pragma unroll
      for (int nt = 0; nt < 4; nt++) {
        int col = n0 + nt * 16 + l16;
        lnb[enc_swz(R, col)] = f2b((acc1[nt][r] - mean) * inv * g1v[col] + b1v[col]);
      }
    }
    __syncthreads();
  }

  // ---- GEMM2: u = ln1 @ w1^T ; he1 = h + silu(u) -> hres, LN2 -> lnb ----
  floatx4 acc2[4] = {};
  enc_gemm(lnb, W1b, Wst, acc2, wave, lane, l16, quad, krot);
  float hval[4][4];
  {
#pragma unroll
    for (int r = 0; r < 4; r++) {
      int R = quad * 4 + r;
      float s = 0.f, q = 0.f;
#pragma unroll
      for (int nt = 0; nt < 4; nt++) {
        int col = n0 + nt * 16 + l16;
        float u = acc2[nt][r];
        float hv = hres[R][col] + u / (1.f + __expf(-u));
        hres[R][col] = hv;
        hval[nt][r] = hv;
        s += hv; q = fmaf(hv, hv, q);
      }
#pragma unroll
      for (int mk = 1; mk < 16; mk <<= 1) { s += __shfl_xor(s, mk, 64); q += __shfl_xor(q, mk, 64); }
      if (l16 == 0) { red[wave][R][0] = s; red[wave][R][1] = q; }
    }
    __syncthreads();
#pragma unroll
    for (int r = 0; r < 4; r++) {
      int R = quad * 4 + r;
      float st = 0.f, qt2 = 0.f;
#pragma unroll
      for (int w2 = 0; w2 < 8; w2++) { st += red[w2][R][0]; qt2 += red[w2][R][1]; }
      float mean = st * (1.f / 512.f);
      float inv = rsqrtf(qt2 * (1.f / 512.f) - mean * mean + 1e-5f);
#pragma unroll
      for (int nt = 0; nt < 4; nt++) {
        int col = n0 + nt * 16 + l16;
        lnb[enc_swz(R, col)] = f2b((hval[nt][r] - mean) * inv * g2v[col] + b2v[col]);
      }
    }
    __syncthreads();
  }

  // ---- GEMM3: w = ln2 @ w2^T ; he2 = he1 + silu(w) -> hres, RMS partials ----
  floatx4 acc3[4] = {};
  enc_gemm(lnb, W2b, Wst, acc3, wave, lane, l16, quad, krot);
  {
#pragma unroll
    for (int r = 0; r < 4; r++) {
      int R = quad * 4 + r;
      float q = 0.f;
#pragma unroll
      for (int nt = 0; nt < 4; nt++) {
        int col = n0 + nt * 16 + l16;
        float u = acc3[nt][r];
        float hv = hres[R][col] + u / (1.f + __expf(-u));
        hres[R][col] = hv;
        q = fmaf(hv, hv, q);
      }
#pragma unroll
      for (int mk = 1; mk < 16; mk <<= 1) q += __shfl_xor(q, mk, 64);
      if (l16 == 0) red[wave][R][1] = q;
    }
    __syncthreads();
  }

  // ---- final: rms-scale + 512->32 proj (fp32) + softplus temp + tanh ----
  {
    const int n = lane & 31, kh = lane >> 5;
    float rinv[2], pacc[2] = {0.f, 0.f};
#pragma unroll
    for (int rr = 0; rr < 2; rr++) {
      int R = wave * 2 + rr;
      float qt2 = 0.f;
#pragma unroll
      for (int w2 = 0; w2 < 8; w2++) qt2 += red[w2][R][1];
      rinv[rr] = rsqrtf(qt2 * (1.f / 512.f) + 1e-6f);
    }
    for (int kc = 0; kc < 64; kc++) {
      int k = kh * 256 + kc * 4;
      float4 wv = *(const float4*)(wout + (size_t)n * 512 + k);
#pragma unroll
      for (int rr = 0; rr < 2; rr++) {
        float4 hv = *(const float4*)&hres[wave * 2 + rr][k];
        pacc[rr] = fmaf(wv.x, hv.x, fmaf(wv.y, hv.y, fmaf(wv.z, hv.z, fmaf(wv.w, hv.w, pacc[rr]))));
      }
    }
#pragma unroll
    for (int rr = 0; rr < 2; rr++) pacc[rr] += __shfl_xor(pacc[rr], 32, 64);
    if (kh == 0) {
      float c = ct[n];
      float sp = (c > 20.f) ? c : log1pf(__expf(c));
#pragma unroll
      for (int rr = 0; rr < 2; rr++)
        z[(size_t)(row0 + wave * 2 + rr) * 32 + n] = tanhf(pacc[rr] * rinv[rr] / (sp + 1e-4f));
    }
  }
}

extern "C" void kernel_launch(void* const* d_in, const int* in_sizes, int n_in,
                              void* d_out, int out_size, void* d_ws, size_t ws_size,
                              hipStream_t stream) {
  const float* x = (const float*)d_in[0];
  const float* qp = (const float*)d_in[1];
  const float* kp = (const float*)d_in[2];
  const float* wv = (const float*)d_in[3];
  const float* wpr = (const float*)d_in[4];
  const float* qg = (const float*)d_in[5];
  const float* w0 = (const float*)d_in[6];
  const float* g1 = (const float*)d_in[7];
  const float* b1 = (const float*)d_in[8];
  const float* w1 = (const float*)d_in[9];
  const float* g2 = (const float*)d_in[10];
  const float* b2 = (const float*)d_in[11];
  const float* w2 = (const float*)d_in[12];
  const float* wout = (const float*)d_in[13];
  const float* ct = (const float*)d_in[14];
  float* z = (float*)d_out;

  float* ws = (float*)d_ws;
  const size_t MEG = 1024 * 1024;
  float* A_QKV = ws;                          // [0..4M) fp32 qkv
  u16* A_Qb = (u16*)(ws + 4 * MEG);           // [4M..4.5M)
  u16* A_Kb = (u16*)(ws + 4 * MEG + 524288);  // [4.5M..5M)
  u16* A_Vt = (u16*)(ws + 5 * MEG);           // [5M..6M)
  float* A_PO = ws + 6 * MEG;                 // [6M..10M): split-K partial O (4M floats)
  u16* A_Y2b = (u16*)(ws + 10 * MEG);         // [10M..11M)
  float* A_H = ws + 11 * MEG;                 // [11M..13M) fp32 h (4096x512)
  u16* XB = (u16*)(ws + 13 * MEG);            // [13M..14M)
  float* A_PL = ws + 13 * MEG;                // PL after XB dead (post-QKV gemm)
  u16* WCATb = (u16*)(ws + 14 * MEG);         // [14M..14.25M)
  u16* WPRb = WCATb + 524288;
  u16* W0b = WPRb + 262144;
  u16* W1b = W0b + 262144;
  u16* W2b = W1b + 262144;

  hipLaunchKernelGGL(prep_cast, dim3(5120), dim3(256), 0, stream, x, wpr, w0, w1, w2, qp, kp, wv,
                     XB, WPRb, W0b, W1b, W2b, WCATb);
  hipLaunchKernelGGL((mgemm<0, false>), dim3(16, 64), dim3(256), 0, stream, XB, WCATb,
                     (const float*)nullptr, A_QKV, (u16*)nullptr, 1024);
  hipLaunchKernelGGL(prep_attn, dim3(2560), dim3(256), 0, stream, A_QKV, qg, A_Qb, A_Kb, A_Vt);
  hipLaunchKernelGGL(attn_split, dim3(1024), dim3(256), 0, stream, A_Qb, A_Kb, A_Vt, A_PO, A_PL);
  hipLaunchKernelGGL(attn_combine, dim3(8192), dim3(256), 0, stream, A_PO, A_PL, A_QKV, A_Y2b);
  // h = y2 @ wpr^T + x   (fp32 only; enc_fused casts in-kernel)
  hipLaunchKernelGGL((mgemm<1, false>), dim3(8, 64), dim3(256), 0, stream, A_Y2b, WPRb, x, A_H,
                     (u16*)nullptr, 512);
  // fused encoder chain + final head
  hipLaunchKernelGGL(enc_fused, dim3(256), dim3(512), 0, stream, A_H, W0b, W1b, W2b,
                     g1, b1, g2, b2, wout, ct, z);
}

// Round 12
// 185.214 us; speedup vs baseline: 1.0164x; 1.0164x over previous
//
#include <hip/hip_runtime.h>
#include <math.h>

typedef unsigned short u16;
typedef __attribute__((ext_vector_type(8))) short short8;
typedef __attribute__((ext_vector_type(4))) float floatx4;

__device__ __forceinline__ float b2f(u16 u) { return __uint_as_float(((unsigned)u) << 16); }
__device__ __forceinline__ u16 f2b(float f) {
  unsigned u = __float_as_uint(f);
  return (u16)((u + 0x7fffu + ((u >> 16) & 1u)) >> 16);
}

// ---------- fused prep: cast x -> bf16 | cast 4 weights | build Wcat ----------
// W0/W1/W2 are emitted in MFMA-fragment-major layout: per (ntile16, kchunk32) a 1KB
// block ordered lane*8+e. A wave's B-fragment load is then ONE contiguous 1KB burst.
__global__ __launch_bounds__(256) void prep_cast(const float* __restrict__ x, const float* __restrict__ wpr,
                                                 const float* __restrict__ w0, const float* __restrict__ w1,
                                                 const float* __restrict__ w2, const float* __restrict__ qp,
                                                 const float* __restrict__ kp, const float* __restrict__ wv,
                                                 u16* __restrict__ XB, u16* __restrict__ WPRb,
                                                 u16* __restrict__ W0b, u16* __restrict__ W1b,
                                                 u16* __restrict__ W2b, u16* __restrict__ wcat) {
  int bi = blockIdx.x, tid = threadIdx.x;
  if (bi < 2048) {                       // cast_x: 524288 float4s
    int i = bi * 256 + tid;
    float4 v = ((const float4*)x)[i];
    ushort4 o; o.x = f2b(v.x); o.y = f2b(v.y); o.z = f2b(v.z); o.w = f2b(v.w);
    ((ushort4*)XB)[i] = o;
  } else if (bi < 3072) {                // cast 4x 512x512 weights: 262144 float4s
    int i = (bi - 2048) * 256 + tid;
    int sel = i >> 16, j = i & 65535;
    const float* s = sel == 0 ? wpr : sel == 1 ? w0 : sel == 2 ? w1 : w2;
    float4 v = ((const float4*)s)[j];
    ushort4 o; o.x = f2b(v.x); o.y = f2b(v.y); o.z = f2b(v.z); o.w = f2b(v.w);
    if (sel == 0) {
      ((ushort4*)WPRb)[j] = o;           // row-major (mgemm path)
    } else {                             // fragment-major scatter (enc_fused path)
      u16* d = sel == 1 ? W0b : sel == 2 ? W1b : W2b;
      int n = j >> 7, k4 = (j & 127) << 2;        // n row, k col (aligned 4)
      int lane = (((k4 >> 3) & 3) << 4) | (n & 15);
      int dst = (((n >> 4) * 16 + (k4 >> 5)) << 9) + lane * 8 + (k4 & 7);
      *(ushort4*)(d + dst) = o;
    }
  } else {                               // build_wcat: 524288 elements
    int i = (bi - 3072) * 256 + tid;
    int d = i & 511, c = i >> 9;
    float v;
    if (c < 512) {
      int hh = c >> 5, o = c & 31;
      const float* src = (hh < 8) ? qp : kp;
      int h = hh & 7;
      v = src[(h * 512 + d) * 32 + o];
    } else {
      v = wv[(c - 512) * 512 + d];
    }
    wcat[i] = f2b(v);
  }
}

// ---------- bf16 MFMA GEMM v2 (verified 223us baseline): BK=64, register prefetch ----------
// C[M x N] = A[M x 512] @ B^T.  EPI: 0 plain, 1 +X, 2 X + silu(acc). DUAL: also store bf16.
template <int EPI, bool DUAL>
__global__ __launch_bounds__(256) void mgemm(const u16* __restrict__ A, const u16* __restrict__ Bw,
                                             const float* __restrict__ X, float* __restrict__ C,
                                             u16* __restrict__ Cb, int N) {
  __shared__ u16 As[64][72];  // stride 144B = 9*16 (b128-aligned), banks 2-way max
  __shared__ u16 Bs[64][72];
  const int tid = threadIdx.x;
  const int bm = blockIdx.y, bn = blockIdx.x;
  const int lane = tid & 63, wave = tid >> 6;
  const int wm = wave >> 1, wn = wave & 1;
  const int quad = lane >> 4, l16 = lane & 15;
  const int sr = tid >> 2;        // staging row 0..63
  const int sk = (tid & 3) << 4;  // k-chunk 0,16,32,48
  floatx4 acc[2][2] = {};
  const u16* Ap = A + (size_t)(bm * 64 + sr) * 512 + sk;
  const u16* Bp = Bw + (size_t)(bn * 64 + sr) * 512 + sk;
  uint4 a0 = *(const uint4*)(Ap);
  uint4 a1 = *(const uint4*)(Ap + 8);
  uint4 b0 = *(const uint4*)(Bp);
  uint4 b1 = *(const uint4*)(Bp + 8);
  for (int k0 = 0; k0 < 512; k0 += 64) {
    __syncthreads();
    *(uint4*)&As[sr][sk] = a0;
    *(uint4*)&As[sr][sk + 8] = a1;
    *(uint4*)&Bs[sr][sk] = b0;
    *(uint4*)&Bs[sr][sk + 8] = b1;
    __syncthreads();
    if (k0 + 64 < 512) {  // prefetch next tile; latency overlaps MFMAs below
      a0 = *(const uint4*)(Ap + k0 + 64);
      a1 = *(const uint4*)(Ap + k0 + 72);
      b0 = *(const uint4*)(Bp + k0 + 64);
      b1 = *(const uint4*)(Bp + k0 + 72);
    }
#pragma unroll
    for (int kk = 0; kk < 2; kk++) {
      short8 af0 = *(const short8*)&As[wm * 32 + l16][kk * 32 + quad * 8];
      short8 af1 = *(const short8*)&As[wm * 32 + 16 + l16][kk * 32 + quad * 8];
      short8 bf0 = *(const short8*)&Bs[wn * 32 + l16][kk * 32 + quad * 8];
      short8 bf1 = *(const short8*)&Bs[wn * 32 + 16 + l16][kk * 32 + quad * 8];
      acc[0][0] = __builtin_amdgcn_mfma_f32_16x16x32_bf16(af0, bf0, acc[0][0], 0, 0, 0);
      acc[0][1] = __builtin_amdgcn_mfma_f32_16x16x32_bf16(af0, bf1, acc[0][1], 0, 0, 0);
      acc[1][0] = __builtin_amdgcn_mfma_f32_16x16x32_bf16(af1, bf0, acc[1][0], 0, 0, 0);
      acc[1][1] = __builtin_amdgcn_mfma_f32_16x16x32_bf16(af1, bf1, acc[1][1], 0, 0, 0);
    }
  }
#pragma unroll
  for (int mt = 0; mt < 2; mt++)
#pragma unroll
    for (int r = 0; r < 4; r++) {
      int row = bm * 64 + wm * 32 + mt * 16 + quad * 4 + r;
#pragma unroll
      for (int nt = 0; nt < 2; nt++) {
        int col = bn * 64 + wn * 32 + nt * 16 + l16;
        float v = acc[mt][nt][r];
        if (EPI == 1) {
          v += X[(size_t)row * 512 + col];
        } else if (EPI == 2) {
          float xv = X[(size_t)row * 512 + col];
          v = xv + v / (1.f + __expf(-v));
        }
        C[(size_t)row * N + col] = v;
        if (DUAL) Cb[(size_t)row * N + col] = f2b(v);
      }
    }
}

// ---------- fused prep_attn: RoPE q,k -> bf16 (b,h,t,32) | V -> bf16 (b,h,64,T) ----------
// q-gain additionally folds log2(e) so attn_split can use v_exp_f32 (exp2) directly.
__global__ __launch_bounds__(256) void prep_attn(const float* __restrict__ qkv, const float* __restrict__ qgain,
                                                 u16* __restrict__ qr, u16* __restrict__ kr,
                                                 u16* __restrict__ Vt) {
  const int bi = blockIdx.x, tid = threadIdx.x;
  if (bi < 2048) {  // RoPE
    int gid = bi * 256 + tid;
    int o = gid & 15;
    int t = (gid >> 4) & 2047;
    int h = (gid >> 15) & 7;
    int b = gid >> 18;
    const float* row = qkv + (size_t)(b * 2048 + t) * 1024;
    float freq = powf(10000.f, -(float)o / 16.f);
    float ang = (float)t * freq;
    float s, c;
    sincosf(ang, &s, &c);
    // gain * 1/sqrt(32) * log2(e)  (exp2-based softmax downstream)
    float g = qgain[h] * (0.17677669529663687f * 1.4426950408889634f);
    int qb = h * 32;
    float q0 = row[qb + o], q1 = row[qb + o + 16];
    float k0 = row[256 + qb + o], k1 = row[256 + qb + o + 16];
    u16* qo = qr + ((size_t)((b * 8 + h) * 2048 + t)) * 32;
    u16* ko = kr + ((size_t)((b * 8 + h) * 2048 + t)) * 32;
    qo[o] = f2b((q0 * c - q1 * s) * g);
    qo[o + 16] = f2b((q1 * c + q0 * s) * g);
    ko[o] = f2b(k0 * c - k1 * s);
    ko[o + 16] = f2b(k1 * c + k0 * s);
  } else {  // V transpose
    int idx = bi - 2048;
    const int tt = idx & 31, bh = idx >> 5;
    const int b = bh >> 3, h = bh & 7;
    __shared__ u16 Ts[64][72];
    const int r = tid >> 2, q = tid & 3;
    const float* src = qkv + ((size_t)(b * 2048 + tt * 64 + r)) * 1024 + 512 + h * 64 + q * 16;
#pragma unroll
    for (int j = 0; j < 4; j++) {
      float4 v = *(const float4*)(src + j * 4);
      Ts[q * 16 + j * 4 + 0][r] = f2b(v.x);
      Ts[q * 16 + j * 4 + 1][r] = f2b(v.y);
      Ts[q * 16 + j * 4 + 2][r] = f2b(v.z);
      Ts[q * 16 + j * 4 + 3][r] = f2b(v.w);
    }
    __syncthreads();
    u16* dst = Vt + ((size_t)(bh * 64 + r)) * 2048 + tt * 64 + q * 16;
    *(uint4*)dst = *(const uint4*)&Ts[r][q * 16];
    *(uint4*)(dst + 8) = *(const uint4*)&Ts[r][q * 16 + 8];
  }
}

// ---------- MFMA causal attention, split-K (S=2), no-max softmax (exp2), K/V prefetch ----------
// + T5 s_setprio around MFMA clusters: 4 independent blocks/CU at staggered phases
// (the m191 attention regime where setprio measured +4-7%; null only in lockstep GEMMs).
__global__ __launch_bounds__(256) void attn_split(const u16* __restrict__ Qb, const u16* __restrict__ Kb,
                                                  const u16* __restrict__ Vt, float* __restrict__ PO,
                                                  float* __restrict__ PL) {
  const int bi = blockIdx.x;               // 1024 blocks
  const int bh = bi & 15;
  const int q0i = (bi >> 4) & 15;
  const int rem = bi >> 8;                 // blocks j,j+256,j+512,j+768 share a CU:
  const int qt = (rem & 1) ? (31 - q0i) : q0i;  // per-CU work = const 33 iters
  const int s = rem >> 1;
  const int tid = threadIdx.x;
  const int w = tid >> 6, lane = tid & 63, quad = lane >> 4, l16 = lane & 15;
  __shared__ u16 Vts[64][72];
  __shared__ u16 Ps[4][16][72];

  const int mid = (qt + 1) >> 1;
  const int kt_beg = s ? mid : 0;
  const int kt_end = s ? (qt + 1) : mid;

  short8 qfrag = *(const short8*)(Qb + ((size_t)(bh * 2048 + qt * 64 + w * 16 + l16)) * 32 + quad * 8);
  floatx4 o_acc[4] = {};
  float l_part[4] = {0.f, 0.f, 0.f, 0.f};
  const u16* Kbase = Kb + (size_t)bh * 2048 * 32;
  const u16* Vtb = Vt + (size_t)bh * 64 * 2048;
  const int vr = tid >> 2, vc = (tid & 3) << 4;

  uint4 v0 = {}, v1 = {};
  short8 kf[4] = {};
  if (kt_beg < kt_end) {
    const u16* src = Vtb + (size_t)vr * 2048 + kt_beg * 64 + vc;
    v0 = *(const uint4*)src;
    v1 = *(const uint4*)(src + 8);
#pragma unroll
    for (int nt = 0; nt < 4; nt++)
      kf[nt] = *(const short8*)(Kbase + (size_t)(kt_beg * 64 + nt * 16 + l16) * 32 + quad * 8);
  }

  for (int kt = kt_beg; kt < kt_end; ++kt) {
    __syncthreads();
    *(uint4*)&Vts[vr][vc] = v0;
    *(uint4*)&Vts[vr][vc + 8] = v1;
    __syncthreads();
    const bool more = (kt + 1 < kt_end);
    uint4 v0n = {}, v1n = {};
    short8 kfn[4] = {};
    if (more) {  // prefetch next K/V; latency overlaps exp+MFMA below
      const u16* src = Vtb + (size_t)vr * 2048 + (kt + 1) * 64 + vc;
      v0n = *(const uint4*)src;
      v1n = *(const uint4*)(src + 8);
#pragma unroll
      for (int nt = 0; nt < 4; nt++)
        kfn[nt] = *(const short8*)(Kbase + (size_t)((kt + 1) * 64 + nt * 16 + l16) * 32 + quad * 8);
    }

    floatx4 s_acc[4];
    __builtin_amdgcn_s_setprio(1);
#pragma unroll
    for (int nt = 0; nt < 4; nt++) {
      floatx4 zz = {0.f, 0.f, 0.f, 0.f};
      s_acc[nt] = __builtin_amdgcn_mfma_f32_16x16x32_bf16(qfrag, kf[nt], zz, 0, 0, 0);
    }
    __builtin_amdgcn_s_setprio(0);
    const bool diag = (kt == qt);
#pragma unroll
    for (int r = 0; r < 4; r++) {
      int mloc = w * 16 + quad * 4 + r;
      float psum = 0.f;
#pragma unroll
      for (int nt = 0; nt < 4; nt++) {
        float p = __builtin_amdgcn_exp2f(s_acc[nt][r]);  // log2e folded into q-gain
        if (diag && (nt * 16 + l16) > mloc) p = 0.f;
        psum += p;
        Ps[w][quad * 4 + r][nt * 16 + l16] = f2b(p);
      }
      l_part[r] += psum;
    }
    __builtin_amdgcn_s_setprio(1);
#pragma unroll
    for (int kc = 0; kc < 2; kc++) {
      short8 pf = *(const short8*)&Ps[w][l16][kc * 32 + quad * 8];
#pragma unroll
      for (int nt = 0; nt < 4; nt++) {
        short8 vf = *(const short8*)&Vts[nt * 16 + l16][kc * 32 + quad * 8];
        o_acc[nt] = __builtin_amdgcn_mfma_f32_16x16x32_bf16(pf, vf, o_acc[nt], 0, 0, 0);
      }
    }
    __builtin_amdgcn_s_setprio(0);
    v0 = v0n; v1 = v1n;
#pragma unroll
    for (int nt = 0; nt < 4; nt++) kf[nt] = kfn[nt];
  }

  // store partials (unnormalized O, per-row l)
  const int pidx = (bh * 32 + qt) * 2 + s;
  float* pob = PO + (size_t)pidx * 4096;
#pragma unroll
  for (int r = 0; r < 4; r++) {
    float ls = l_part[r];
#pragma unroll
    for (int mk = 1; mk < 16; mk <<= 1) ls += __shfl_xor(ls, mk, 64);
    int row = w * 16 + quad * 4 + r;
#pragma unroll
    for (int nt = 0; nt < 4; nt++) pob[row * 64 + nt * 16 + l16] = o_acc[nt][r];
    if (l16 == 0) PL[pidx * 64 + row] = ls;
  }
}

// ---------- combine split-K partials + self-align + permute to (b,t,512) bf16 ----------
// grid must be 8192: 32768 (bh,tok) rows, 4 per block.
__global__ __launch_bounds__(256) void attn_combine(const float* __restrict__ PO, const float* __restrict__ PL,
                                                    const float* __restrict__ qkv, u16* __restrict__ y2b) {
  int ridx = blockIdx.x * 4 + (threadIdx.x >> 6);  // 0..32767
  int lane = threadIdx.x & 63;
  int bh = ridx >> 11, tok = ridx & 2047;
  int qt = tok >> 6, row = tok & 63;
  int pidx = (bh * 32 + qt) * 2;
  const float* p0 = PO + (size_t)pidx * 4096 + row * 64;
  float o = p0[lane] + p0[4096 + lane];
  float l = PL[pidx * 64 + row] + PL[(pidx + 1) * 64 + row];
  float yv = o / l;
  int b = bh >> 3, h = bh & 7;
  float vv = qkv[(size_t)(b * 2048 + tok) * 1024 + 512 + h * 64 + lane];
  float ss = vv * vv, dot = yv * vv;
#pragma unroll
  for (int mk = 1; mk < 64; mk <<= 1) {
    ss += __shfl_xor(ss, mk, 64);
    dot += __shfl_xor(dot, mk, 64);
  }
  float coef = dot / fmaxf(ss, 1e-24f);
  y2b[(size_t)(b * 2048 + tok) * 512 + h * 64 + lane] = f2b(yv - coef * vv);
}

// ---------- fused encoder: he0 -> ln1 -> he1 -> ln2 -> he2 -> rms -> proj -> z ----------
// v6 (r9 verified best, 41.6us): plain fragment-major loads + per-XCD k-phase krot.
// 7 structures measured 41-57us; per-CU weight stream pinned at ~16 B/cy with 1
// block/CU (no co-resident block to cover VMEM stalls; m114 overlap unavailable).
#define HPAD 516  // hres row stride (floats)

__device__ __forceinline__ int enc_swz(int row, int col) {
  // u16 element index into [16][512]; XOR 16B-chunk swizzle kills the 1KB-stride bank conflict
  return row * 512 + ((((col >> 3) ^ (row & 7)) << 3) | (col & 7));
}

__device__ __forceinline__ void enc_gemm(const u16* __restrict__ inb, const u16* __restrict__ Wf,
                                         floatx4* acc, int wave, int l16, int quad, int lane, int krot) {
  // B-fragment loads: fragment-major layout, one contiguous 1KB burst per (ntile,kc)
  const u16* wb = Wf + ((size_t)(wave * 4 * 16) << 9) + lane * 8;  // ntile = wave*4+nt
  short8 aB[4];
  short8 bB[4][4];
#pragma unroll
  for (int p = 0; p < 4; p++) {
    const int kc = (p + krot) & 15;
    aB[p] = *(const short8*)(inb + enc_swz(l16, kc * 32 + quad * 8));
#pragma unroll
    for (int nt = 0; nt < 4; nt++)
      bB[p][nt] = *(const short8*)(wb + (((nt * 16) + kc) << 9));
  }
#pragma unroll
  for (int ks = 0; ks < 16; ks++) {
    const int cur = ks & 3;
#pragma unroll
    for (int nt = 0; nt < 4; nt++)
      acc[nt] = __builtin_amdgcn_mfma_f32_16x16x32_bf16(aB[cur], bB[cur][nt], acc[nt], 0, 0, 0);
    if (ks + 4 < 16) {  // refill slot 'cur' with step ks+4
      const int kn = (ks + 4 + krot) & 15;
      aB[cur] = *(const short8*)(inb + enc_swz(l16, kn * 32 + quad * 8));
#pragma unroll
      for (int nt = 0; nt < 4; nt++)
        bB[cur][nt] = *(const short8*)(wb + (((nt * 16) + kn) << 9));
    }
  }
}

__global__ __launch_bounds__(512) void enc_fused(const float* __restrict__ H, const u16* __restrict__ W0b,
                                                 const u16* __restrict__ W1b, const u16* __restrict__ W2b,
                                                 const float* __restrict__ g1v, const float* __restrict__ b1v,
                                                 const float* __restrict__ g2v, const float* __restrict__ b2v,
                                                 const float* __restrict__ wout, const float* __restrict__ ct,
                                                 float* __restrict__ z) {
  __shared__ u16 curb[16 * 512];      // bf16 h (GEMM1 input), swizzled
  __shared__ u16 lnb[16 * 512];       // bf16 ln output (GEMM2/3 input), swizzled
  __shared__ float hres[16][HPAD];    // fp32 residual h -> he1 -> he2 (padded rows)
  __shared__ float red[8][16][2];     // per-wave per-row (sum, sumsq)

  const int tid = threadIdx.x;
  const int wave = tid >> 6, lane = tid & 63, quad = lane >> 4, l16 = lane & 15;
  const int row0 = blockIdx.x * 16;
  const int n0 = wave * 64;
  const int krot = (blockIdx.x >> 3) & 15;  // 16 distinct phases among each XCD's 32 blocks

  // ---- load h rows: fp32 -> hres, cast -> curb ----
#pragma unroll
  for (int j = 0; j < 4; j++) {
    int idx = j * 512 + tid;          // 2048 float4s
    int row = idx >> 7, c4 = idx & 127;
    float4 v = ((const float4*)H)[(size_t)(row0 + row) * 128 + c4];
    *(float4*)&hres[row][c4 * 4] = v;
    int col = c4 * 4;
    curb[enc_swz(row, col + 0)] = f2b(v.x);
    curb[enc_swz(row, col + 1)] = f2b(v.y);
    curb[enc_swz(row, col + 2)] = f2b(v.z);
    curb[enc_swz(row, col + 3)] = f2b(v.w);
  }
  __syncthreads();

  // ---- GEMM1: he0 = h @ w0^T ----
  floatx4 acc1[4] = {};
  enc_gemm(curb, W0b, acc1, wave, l16, quad, lane, krot);

  // ---- LN1 -> lnb (bf16) ----
  {
#pragma unroll
    for (int r = 0; r < 4; r++) {
      float s = 0.f, q = 0.f;
#pragma unroll
      for (int nt = 0; nt < 4; nt++) { float v = acc1[nt][r]; s += v; q = fmaf(v, v, q); }
#pragma unroll
      for (int mk = 1; mk < 16; mk <<= 1) { s += __shfl_xor(s, mk, 64); q += __shfl_xor(q, mk, 64); }
      if (l16 == 0) { red[wave][quad * 4 + r][0] = s; red[wave][quad * 4 + r][1] = q; }
    }
    __syncthreads();
#pragma unroll
    for (int r = 0; r < 4; r++) {
      int R = quad * 4 + r;
      float st = 0.f, qt2 = 0.f;
#pragma unroll
      for (int w2 = 0; w2 < 8; w2++) { st += red[w2][R][0]; qt2 += red[w2][R][1]; }
      float mean = st * (1.f / 512.f);
      float inv = rsqrtf(qt2 * (1.f / 512.f) - mean * mean + 1e-5f);
#pragma unroll
      for (int nt = 0; nt < 4; nt++) {
        int col = n0 + nt * 16 + l16;
        lnb[enc_swz(R, col)] = f2b((acc1[nt][r] - mean) * inv * g1v[col] + b1v[col]);
      }
    }
    __syncthreads();
  }

  // ---- GEMM2: u = ln1 @ w1^T ; he1 = h + silu(u) -> hres, LN2 -> lnb ----
  floatx4 acc2[4] = {};
  enc_gemm(lnb, W1b, acc2, wave, l16, quad, lane, krot);
  float hval[4][4];
  {
#pragma unroll
    for (int r = 0; r < 4; r++) {
      int R = quad * 4 + r;
      float s = 0.f, q = 0.f;
#pragma unroll
      for (int nt = 0; nt < 4; nt++) {
        int col = n0 + nt * 16 + l16;
        float u = acc2[nt][r];
        float hv = hres[R][col] + u / (1.f + __expf(-u));
        hres[R][col] = hv;
        hval[nt][r] = hv;
        s += hv; q = fmaf(hv, hv, q);
      }
#pragma unroll
      for (int mk = 1; mk < 16; mk <<= 1) { s += __shfl_xor(s, mk, 64); q += __shfl_xor(q, mk, 64); }
      if (l16 == 0) { red[wave][R][0] = s; red[wave][R][1] = q; }
    }
    __syncthreads();
#pragma unroll
    for (int r = 0; r < 4; r++) {
      int R = quad * 4 + r;
      float st = 0.f, qt2 = 0.f;
#pragma unroll
      for (int w2 = 0; w2 < 8; w2++) { st += red[w2][R][0]; qt2 += red[w2][R][1]; }
      float mean = st * (1.f / 512.f);
      float inv = rsqrtf(qt2 * (1.f / 512.f) - mean * mean + 1e-5f);
#pragma unroll
      for (int nt = 0; nt < 4; nt++) {
        int col = n0 + nt * 16 + l16;
        lnb[enc_swz(R, col)] = f2b((hval[nt][r] - mean) * inv * g2v[col] + b2v[col]);
      }
    }
    __syncthreads();
  }

  // ---- GEMM3: w = ln2 @ w2^T ; he2 = he1 + silu(w) -> hres, RMS partials ----
  floatx4 acc3[4] = {};
  enc_gemm(lnb, W2b, acc3, wave, l16, quad, lane, krot);
  {
#pragma unroll
    for (int r = 0; r < 4; r++) {
      int R = quad * 4 + r;
      float q = 0.f;
#pragma unroll
      for (int nt = 0; nt < 4; nt++) {
        int col = n0 + nt * 16 + l16;
        float u = acc3[nt][r];
        float hv = hres[R][col] + u / (1.f + __expf(-u));
        hres[R][col] = hv;
        q = fmaf(hv, hv, q);
      }
#pragma unroll
      for (int mk = 1; mk < 16; mk <<= 1) q += __shfl_xor(q, mk, 64);
      if (l16 == 0) red[wave][R][1] = q;
    }
    __syncthreads();
  }

  // ---- final: rms-scale + 512->32 proj (fp32) + softplus temp + tanh ----
  {
    const int n = lane & 31, kh = lane >> 5;
    float rinv[2], pacc[2] = {0.f, 0.f};
#pragma unroll
    for (int rr = 0; rr < 2; rr++) {
      int R = wave * 2 + rr;
      float qt2 = 0.f;
#pragma unroll
      for (int w2 = 0; w2 < 8; w2++) qt2 += red[w2][R][1];
      rinv[rr] = rsqrtf(qt2 * (1.f / 512.f) + 1e-6f);
    }
    for (int kc = 0; kc < 64; kc++) {
      int k = kh * 256 + kc * 4;
      float4 wv = *(const float4*)(wout + (size_t)n * 512 + k);
#pragma unroll
      for (int rr = 0; rr < 2; rr++) {
        float4 hv = *(const float4*)&hres[wave * 2 + rr][k];
        pacc[rr] = fmaf(wv.x, hv.x, fmaf(wv.y, hv.y, fmaf(wv.z, hv.z, fmaf(wv.w, hv.w, pacc[rr]))));
      }
    }
#pragma unroll
    for (int rr = 0; rr < 2; rr++) pacc[rr] += __shfl_xor(pacc[rr], 32, 64);
    if (kh == 0) {
      float c = ct[n];
      float sp = (c > 20.f) ? c : log1pf(__expf(c));
#pragma unroll
      for (int rr = 0; rr < 2; rr++)
        z[(size_t)(row0 + wave * 2 + rr) * 32 + n] = tanhf(pacc[rr] * rinv[rr] / (sp + 1e-4f));
    }
  }
}

extern "C" void kernel_launch(void* const* d_in, const int* in_sizes, int n_in,
                              void* d_out, int out_size, void* d_ws, size_t ws_size,
                              hipStream_t stream) {
  const float* x = (const float*)d_in[0];
  const float* qp = (const float*)d_in[1];
  const float* kp = (const float*)d_in[2];
  const float* wv = (const float*)d_in[3];
  const float* wpr = (const float*)d_in[4];
  const float* qg = (const float*)d_in[5];
  const float* w0 = (const float*)d_in[6];
  const float* g1 = (const float*)d_in[7];
  const float* b1 = (const float*)d_in[8];
  const float* w1 = (const float*)d_in[9];
  const float* g2 = (const float*)d_in[10];
  const float* b2 = (const float*)d_in[11];
  const float* w2 = (const float*)d_in[12];
  const float* wout = (const float*)d_in[13];
  const float* ct = (const float*)d_in[14];
  float* z = (float*)d_out;

  float* ws = (float*)d_ws;
  const size_t MEG = 1024 * 1024;
  float* A_QKV = ws;                          // [0..4M) fp32 qkv
  u16* A_Qb = (u16*)(ws + 4 * MEG);           // [4M..4.5M)
  u16* A_Kb = (u16*)(ws + 4 * MEG + 524288);  // [4.5M..5M)
  u16* A_Vt = (u16*)(ws + 5 * MEG);           // [5M..6M)
  float* A_PO = ws + 6 * MEG;                 // [6M..10M): split-K partial O (4M floats)
  u16* A_Y2b = (u16*)(ws + 10 * MEG);         // [10M..11M)
  float* A_H = ws + 11 * MEG;                 // [11M..13M) fp32 h (4096x512)
  u16* XB = (u16*)(ws + 13 * MEG);            // [13M..14M)
  float* A_PL = ws + 13 * MEG;                // PL after XB dead (post-QKV gemm)
  u16* WCATb = (u16*)(ws + 14 * MEG);         // [14M..14.25M)
  u16* WPRb = WCATb + 524288;
  u16* W0b = WPRb + 262144;
  u16* W1b = W0b + 262144;
  u16* W2b = W1b + 262144;

  hipLaunchKernelGGL(prep_cast, dim3(5120), dim3(256), 0, stream, x, wpr, w0, w1, w2, qp, kp, wv,
                     XB, WPRb, W0b, W1b, W2b, WCATb);
  hipLaunchKernelGGL((mgemm<0, false>), dim3(16, 64), dim3(256), 0, stream, XB, WCATb,
                     (const float*)nullptr, A_QKV, (u16*)nullptr, 1024);
  hipLaunchKernelGGL(prep_attn, dim3(2560), dim3(256), 0, stream, A_QKV, qg, A_Qb, A_Kb, A_Vt);
  hipLaunchKernelGGL(attn_split, dim3(1024), dim3(256), 0, stream, A_Qb, A_Kb, A_Vt, A_PO, A_PL);
  hipLaunchKernelGGL(attn_combine, dim3(8192), dim3(256), 0, stream, A_PO, A_PL, A_QKV, A_Y2b);
  // h = y2 @ wpr^T + x   (fp32 only; enc_fused casts in-kernel)
  hipLaunchKernelGGL((mgemm<1, false>), dim3(8, 64), dim3(256), 0, stream, A_Y2b, WPRb, x, A_H,
                     (u16*)nullptr, 512);
  // fused encoder chain + final head
  hipLaunchKernelGGL(enc_fused, dim3(256), dim3(512), 0, stream, A_H, W0b, W1b, W2b,
                     g1, b1, g2, b2, wout, ct, z);
}

// Round 14
// 180.973 us; speedup vs baseline: 1.0402x; 1.0234x over previous
//
#include <hip/hip_runtime.h>
#include <math.h>

typedef unsigned short u16;
typedef __attribute__((ext_vector_type(8))) short short8;
typedef __attribute__((ext_vector_type(4))) float floatx4;

__device__ __forceinline__ float b2f(u16 u) { return __uint_as_float(((unsigned)u) << 16); }
__device__ __forceinline__ u16 f2b(float f) {
  unsigned u = __float_as_uint(f);
  return (u16)((u + 0x7fffu + ((u >> 16) & 1u)) >> 16);
}

// ---------- fused prep: cast x -> bf16 | cast 4 weights | build Wcat ----------
__global__ __launch_bounds__(256) void prep_cast(const float* __restrict__ x, const float* __restrict__ wpr,
                                                 const float* __restrict__ w0, const float* __restrict__ w1,
                                                 const float* __restrict__ w2, const float* __restrict__ qp,
                                                 const float* __restrict__ kp, const float* __restrict__ wv,
                                                 u16* __restrict__ XB, u16* __restrict__ WPRb,
                                                 u16* __restrict__ W0b, u16* __restrict__ W1b,
                                                 u16* __restrict__ W2b, u16* __restrict__ wcat) {
  int bi = blockIdx.x, tid = threadIdx.x;
  if (bi < 2048) {                       // cast_x: 524288 float4s
    int i = bi * 256 + tid;
    float4 v = ((const float4*)x)[i];
    ushort4 o; o.x = f2b(v.x); o.y = f2b(v.y); o.z = f2b(v.z); o.w = f2b(v.w);
    ((ushort4*)XB)[i] = o;
  } else if (bi < 3072) {                // cast 4x 512x512 weights: 262144 float4s
    int i = (bi - 2048) * 256 + tid;
    int sel = i >> 16, j = i & 65535;
    const float* s = sel == 0 ? wpr : sel == 1 ? w0 : sel == 2 ? w1 : w2;
    float4 v = ((const float4*)s)[j];
    ushort4 o; o.x = f2b(v.x); o.y = f2b(v.y); o.z = f2b(v.z); o.w = f2b(v.w);
    if (sel == 0) {
      ((ushort4*)WPRb)[j] = o;           // row-major (mgemm path)
    } else {                             // fragment-major scatter (enc_fused path)
      u16* d = sel == 1 ? W0b : sel == 2 ? W1b : W2b;
      int n = j >> 7, k4 = (j & 127) << 2;        // n row, k col (aligned 4)
      int lane = (((k4 >> 3) & 3) << 4) | (n & 15);
      int dst = (((n >> 4) * 16 + (k4 >> 5)) << 9) + lane * 8 + (k4 & 7);
      *(ushort4*)(d + dst) = o;
    }
  } else {                               // build_wcat: 524288 elements
    int i = (bi - 3072) * 256 + tid;
    int d = i & 511, c = i >> 9;
    float v;
    if (c < 512) {
      int hh = c >> 5, o = c & 31;
      const float* src = (hh < 8) ? qp : kp;
      int h = hh & 7;
      v = src[(h * 512 + d) * 32 + o];
    } else {
      v = wv[(c - 512) * 512 + d];
    }
    wcat[i] = f2b(v);
  }
}

// ---------- bf16 MFMA GEMM v2: BK=64, register prefetch ----------
// C[M x N] = A[M x 512] @ B^T.  EPI: 0 plain, 1 +X, 2 X + silu(acc). DUAL: also store bf16.
template <int EPI, bool DUAL>
__global__ __launch_bounds__(256) void mgemm(const u16* __restrict__ A, const u16* __restrict__ Bw,
                                             const float* __restrict__ X, float* __restrict__ C,
                                             u16* __restrict__ Cb, int N) {
  __shared__ u16 As[64][72];  // stride 144B = 9*16 (b128-aligned), banks 2-way max
  __shared__ u16 Bs[64][72];
  const int tid = threadIdx.x;
  const int bm = blockIdx.y, bn = blockIdx.x;
  const int lane = tid & 63, wave = tid >> 6;
  const int wm = wave >> 1, wn = wave & 1;
  const int quad = lane >> 4, l16 = lane & 15;
  const int sr = tid >> 2;        // staging row 0..63
  const int sk = (tid & 3) << 4;  // k-chunk 0,16,32,48
  floatx4 acc[2][2] = {};
  const u16* Ap = A + (size_t)(bm * 64 + sr) * 512 + sk;
  const u16* Bp = Bw + (size_t)(bn * 64 + sr) * 512 + sk;
  uint4 a0 = *(const uint4*)(Ap);
  uint4 a1 = *(const uint4*)(Ap + 8);
  uint4 b0 = *(const uint4*)(Bp);
  uint4 b1 = *(const uint4*)(Bp + 8);
  for (int k0 = 0; k0 < 512; k0 += 64) {
    __syncthreads();
    *(uint4*)&As[sr][sk] = a0;
    *(uint4*)&As[sr][sk + 8] = a1;
    *(uint4*)&Bs[sr][sk] = b0;
    *(uint4*)&Bs[sr][sk + 8] = b1;
    __syncthreads();
    if (k0 + 64 < 512) {  // prefetch next tile; latency overlaps MFMAs below
      a0 = *(const uint4*)(Ap + k0 + 64);
      a1 = *(const uint4*)(Ap + k0 + 72);
      b0 = *(const uint4*)(Bp + k0 + 64);
      b1 = *(const uint4*)(Bp + k0 + 72);
    }
#pragma unroll
    for (int kk = 0; kk < 2; kk++) {
      short8 af0 = *(const short8*)&As[wm * 32 + l16][kk * 32 + quad * 8];
      short8 af1 = *(const short8*)&As[wm * 32 + 16 + l16][kk * 32 + quad * 8];
      short8 bf0 = *(const short8*)&Bs[wn * 32 + l16][kk * 32 + quad * 8];
      short8 bf1 = *(const short8*)&Bs[wn * 32 + 16 + l16][kk * 32 + quad * 8];
      acc[0][0] = __builtin_amdgcn_mfma_f32_16x16x32_bf16(af0, bf0, acc[0][0], 0, 0, 0);
      acc[0][1] = __builtin_amdgcn_mfma_f32_16x16x32_bf16(af0, bf1, acc[0][1], 0, 0, 0);
      acc[1][0] = __builtin_amdgcn_mfma_f32_16x16x32_bf16(af1, bf0, acc[1][0], 0, 0, 0);
      acc[1][1] = __builtin_amdgcn_mfma_f32_16x16x32_bf16(af1, bf1, acc[1][1], 0, 0, 0);
    }
  }
#pragma unroll
  for (int mt = 0; mt < 2; mt++)
#pragma unroll
    for (int r = 0; r < 4; r++) {
      int row = bm * 64 + wm * 32 + mt * 16 + quad * 4 + r;
#pragma unroll
      for (int nt = 0; nt < 2; nt++) {
        int col = bn * 64 + wn * 32 + nt * 16 + l16;
        float v = acc[mt][nt][r];
        if (EPI == 1) {
          v += X[(size_t)row * 512 + col];
        } else if (EPI == 2) {
          float xv = X[(size_t)row * 512 + col];
          v = xv + v / (1.f + __expf(-v));
        }
        C[(size_t)row * N + col] = v;
        if (DUAL) Cb[(size_t)row * N + col] = f2b(v);
      }
    }
}

// ---------- QKV GEMM with fused RoPE epilogue + V transpose ----------
// Replaces mgemm<0> + prep_attn. Fix vs r13: Vt store uses t-within-batch
// ((bm&31)*64), not the global row (bm*64) - batch 1 was scrambled.
__global__ __launch_bounds__(256) void qkv_gemm(const u16* __restrict__ A, const u16* __restrict__ Bw,
                                                const float* __restrict__ qgain,
                                                u16* __restrict__ Qb, u16* __restrict__ Kb,
                                                u16* __restrict__ Vt, float* __restrict__ Vf) {
  __shared__ u16 As[64][72];
  __shared__ u16 Bs[64][72];
  const int tid = threadIdx.x;
  const int bm = blockIdx.y, bn = blockIdx.x;
  const int lane = tid & 63, wave = tid >> 6;
  const int wm = wave >> 1, wn = wave & 1;
  const int quad = lane >> 4, l16 = lane & 15;
  const int sr = tid >> 2;
  const int sk = (tid & 3) << 4;
  floatx4 acc[2][2] = {};
  const u16* Ap = A + (size_t)(bm * 64 + sr) * 512 + sk;
  const u16* Bp = Bw + (size_t)(bn * 64 + sr) * 512 + sk;
  uint4 a0 = *(const uint4*)(Ap);
  uint4 a1 = *(const uint4*)(Ap + 8);
  uint4 b0 = *(const uint4*)(Bp);
  uint4 b1 = *(const uint4*)(Bp + 8);
  for (int k0 = 0; k0 < 512; k0 += 64) {
    __syncthreads();
    *(uint4*)&As[sr][sk] = a0;
    *(uint4*)&As[sr][sk + 8] = a1;
    *(uint4*)&Bs[sr][sk] = b0;
    *(uint4*)&Bs[sr][sk + 8] = b1;
    __syncthreads();
    if (k0 + 64 < 512) {
      a0 = *(const uint4*)(Ap + k0 + 64);
      a1 = *(const uint4*)(Ap + k0 + 72);
      b0 = *(const uint4*)(Bp + k0 + 64);
      b1 = *(const uint4*)(Bp + k0 + 72);
    }
#pragma unroll
    for (int kk = 0; kk < 2; kk++) {
      short8 af0 = *(const short8*)&As[wm * 32 + l16][kk * 32 + quad * 8];
      short8 af1 = *(const short8*)&As[wm * 32 + 16 + l16][kk * 32 + quad * 8];
      short8 bf0 = *(const short8*)&Bs[wn * 32 + l16][kk * 32 + quad * 8];
      short8 bf1 = *(const short8*)&Bs[wn * 32 + 16 + l16][kk * 32 + quad * 8];
      acc[0][0] = __builtin_amdgcn_mfma_f32_16x16x32_bf16(af0, bf0, acc[0][0], 0, 0, 0);
      acc[0][1] = __builtin_amdgcn_mfma_f32_16x16x32_bf16(af0, bf1, acc[0][1], 0, 0, 0);
      acc[1][0] = __builtin_amdgcn_mfma_f32_16x16x32_bf16(af1, bf0, acc[1][0], 0, 0, 0);
      acc[1][1] = __builtin_amdgcn_mfma_f32_16x16x32_bf16(af1, bf1, acc[1][1], 0, 0, 0);
    }
  }
  if (bn < 8) {
    // ---- q/k RoPE epilogue ----
    const bool isq = (bn < 4);
    const int h = (isq ? bn : bn - 4) * 2 + wn;
    // gain * 1/sqrt(32) * log2(e) for q (exp2 softmax downstream); k raw
    const float gq = isq ? qgain[h] * (0.17677669529663687f * 1.4426950408889634f) : 1.f;
    const float freq = powf(10000.f, -(float)l16 / 16.f);
    u16* outb = (isq ? Qb : Kb);
#pragma unroll
    for (int mt = 0; mt < 2; mt++)
#pragma unroll
      for (int r = 0; r < 4; r++) {
        int row = bm * 64 + wm * 32 + mt * 16 + quad * 4 + r;
        int t = row & 2047, b = row >> 11;
        float s, c;
        sincosf((float)t * freq, &s, &c);
        float q0 = acc[mt][0][r], q1 = acc[mt][1][r];
        u16* base = outb + ((size_t)((b * 8 + h) * 2048 + t)) * 32;
        if (isq) {
          base[l16] = f2b((q0 * c - q1 * s) * gq);
          base[l16 + 16] = f2b((q1 * c + q0 * s) * gq);
        } else {
          base[l16] = f2b(q0 * c - q1 * s);
          base[l16 + 16] = f2b(q1 * c + q0 * s);
        }
      }
  } else {
    // ---- v epilogue: fp32 store + bf16 transpose ----
    const int h = bn - 8;
    const int b = bm >> 5;  // 64 rows per block, 2048 rows per batch
#pragma unroll
    for (int mt = 0; mt < 2; mt++)
#pragma unroll
      for (int r = 0; r < 4; r++) {
        int row = bm * 64 + wm * 32 + mt * 16 + quad * 4 + r;
#pragma unroll
        for (int nt = 0; nt < 2; nt++) {
          int d = wn * 32 + nt * 16 + l16;
          Vf[(size_t)row * 512 + h * 64 + d] = acc[mt][nt][r];
        }
      }
    __syncthreads();  // all waves done reading As/Bs in K-loop
#pragma unroll
    for (int mt = 0; mt < 2; mt++)
#pragma unroll
      for (int r = 0; r < 4; r++) {
        int rl = wm * 32 + mt * 16 + quad * 4 + r;
#pragma unroll
        for (int nt = 0; nt < 2; nt++) {
          int d = wn * 32 + nt * 16 + l16;
          As[d][rl] = f2b(acc[mt][nt][r]);
        }
      }
    __syncthreads();
    const int bh = b * 8 + h;
    const int t0 = (bm & 31) * 64;  // t within batch (FIX: was bm*64)
    const int dim = tid >> 2, ch = (tid & 3) << 4;
    u16* dst = Vt + ((size_t)(bh * 64 + dim)) * 2048 + t0 + ch;
    *(uint4*)dst = *(const uint4*)&As[dim][ch];
    *(uint4*)(dst + 8) = *(const uint4*)&As[dim][ch + 8];
  }
}

// ---------- MFMA causal attention, split-K (S=2), no-max softmax (exp2), K/V prefetch ----------
// + T5 s_setprio around MFMA clusters (verified +, r12).
__global__ __launch_bounds__(256) void attn_split(const u16* __restrict__ Qb, const u16* __restrict__ Kb,
                                                  const u16* __restrict__ Vt, float* __restrict__ PO,
                                                  float* __restrict__ PL) {
  const int bi = blockIdx.x;               // 1024 blocks
  const int bh = bi & 15;
  const int q0i = (bi >> 4) & 15;
  const int rem = bi >> 8;                 // blocks j,j+256,j+512,j+768 share a CU:
  const int qt = (rem & 1) ? (31 - q0i) : q0i;  // per-CU work = const 33 iters
  const int s = rem >> 1;
  const int tid = threadIdx.x;
  const int w = tid >> 6, lane = tid & 63, quad = lane >> 4, l16 = lane & 15;
  __shared__ u16 Vts[64][72];
  __shared__ u16 Ps[4][16][72];

  const int mid = (qt + 1) >> 1;
  const int kt_beg = s ? mid : 0;
  const int kt_end = s ? (qt + 1) : mid;

  short8 qfrag = *(const short8*)(Qb + ((size_t)(bh * 2048 + qt * 64 + w * 16 + l16)) * 32 + quad * 8);
  floatx4 o_acc[4] = {};
  float l_part[4] = {0.f, 0.f, 0.f, 0.f};
  const u16* Kbase = Kb + (size_t)bh * 2048 * 32;
  const u16* Vtb = Vt + (size_t)bh * 64 * 2048;
  const int vr = tid >> 2, vc = (tid & 3) << 4;

  uint4 v0 = {}, v1 = {};
  short8 kf[4] = {};
  if (kt_beg < kt_end) {
    const u16* src = Vtb + (size_t)vr * 2048 + kt_beg * 64 + vc;
    v0 = *(const uint4*)src;
    v1 = *(const uint4*)(src + 8);
#pragma unroll
    for (int nt = 0; nt < 4; nt++)
      kf[nt] = *(const short8*)(Kbase + (size_t)(kt_beg * 64 + nt * 16 + l16) * 32 + quad * 8);
  }

  for (int kt = kt_beg; kt < kt_end; ++kt) {
    __syncthreads();
    *(uint4*)&Vts[vr][vc] = v0;
    *(uint4*)&Vts[vr][vc + 8] = v1;
    __syncthreads();
    const bool more = (kt + 1 < kt_end);
    uint4 v0n = {}, v1n = {};
    short8 kfn[4] = {};
    if (more) {  // prefetch next K/V; latency overlaps exp+MFMA below
      const u16* src = Vtb + (size_t)vr * 2048 + (kt + 1) * 64 + vc;
      v0n = *(const uint4*)src;
      v1n = *(const uint4*)(src + 8);
#pragma unroll
      for (int nt = 0; nt < 4; nt++)
        kfn[nt] = *(const short8*)(Kbase + (size_t)((kt + 1) * 64 + nt * 16 + l16) * 32 + quad * 8);
    }

    floatx4 s_acc[4];
    __builtin_amdgcn_s_setprio(1);
#pragma unroll
    for (int nt = 0; nt < 4; nt++) {
      floatx4 zz = {0.f, 0.f, 0.f, 0.f};
      s_acc[nt] = __builtin_amdgcn_mfma_f32_16x16x32_bf16(qfrag, kf[nt], zz, 0, 0, 0);
    }
    __builtin_amdgcn_s_setprio(0);
    const bool diag = (kt == qt);
#pragma unroll
    for (int r = 0; r < 4; r++) {
      int mloc = w * 16 + quad * 4 + r;
      float psum = 0.f;
#pragma unroll
      for (int nt = 0; nt < 4; nt++) {
        float p = __builtin_amdgcn_exp2f(s_acc[nt][r]);  // log2e folded into q-gain
        if (diag && (nt * 16 + l16) > mloc) p = 0.f;
        psum += p;
        Ps[w][quad * 4 + r][nt * 16 + l16] = f2b(p);
      }
      l_part[r] += psum;
    }
    __builtin_amdgcn_s_setprio(1);
#pragma unroll
    for (int kc = 0; kc < 2; kc++) {
      short8 pf = *(const short8*)&Ps[w][l16][kc * 32 + quad * 8];
#pragma unroll
      for (int nt = 0; nt < 4; nt++) {
        short8 vf = *(const short8*)&Vts[nt * 16 + l16][kc * 32 + quad * 8];
        o_acc[nt] = __builtin_amdgcn_mfma_f32_16x16x32_bf16(pf, vf, o_acc[nt], 0, 0, 0);
      }
    }
    __builtin_amdgcn_s_setprio(0);
    v0 = v0n; v1 = v1n;
#pragma unroll
    for (int nt = 0; nt < 4; nt++) kf[nt] = kfn[nt];
  }

  // store partials (unnormalized O, per-row l)
  const int pidx = (bh * 32 + qt) * 2 + s;
  float* pob = PO + (size_t)pidx * 4096;
#pragma unroll
  for (int r = 0; r < 4; r++) {
    float ls = l_part[r];
#pragma unroll
    for (int mk = 1; mk < 16; mk <<= 1) ls += __shfl_xor(ls, mk, 64);
    int row = w * 16 + quad * 4 + r;
#pragma unroll
    for (int nt = 0; nt < 4; nt++) pob[row * 64 + nt * 16 + l16] = o_acc[nt][r];
    if (l16 == 0) PL[pidx * 64 + row] = ls;
  }
}

// ---------- combine split-K partials + self-align + permute to (b,t,512) bf16 ----------
// grid must be 8192: 32768 (bh,tok) rows, 4 per block. V read from compact fp32 Vf.
__global__ __launch_bounds__(256) void attn_combine(const float* __restrict__ PO, const float* __restrict__ PL,
                                                    const float* __restrict__ Vf, u16* __restrict__ y2b) {
  int ridx = blockIdx.x * 4 + (threadIdx.x >> 6);  // 0..32767
  int lane = threadIdx.x & 63;
  int bh = ridx >> 11, tok = ridx & 2047;
  int qt = tok >> 6, row = tok & 63;
  int pidx = (bh * 32 + qt) * 2;
  const float* p0 = PO + (size_t)pidx * 4096 + row * 64;
  float o = p0[lane] + p0[4096 + lane];
  float l = PL[pidx * 64 + row] + PL[(pidx + 1) * 64 + row];
  float yv = o / l;
  int b = bh >> 3, h = bh & 7;
  float vv = Vf[(size_t)(b * 2048 + tok) * 512 + h * 64 + lane];
  float ss = vv * vv, dot = yv * vv;
#pragma unroll
  for (int mk = 1; mk < 64; mk <<= 1) {
    ss += __shfl_xor(ss, mk, 64);
    dot += __shfl_xor(dot, mk, 64);
  }
  float coef = dot / fmaxf(ss, 1e-24f);
  y2b[(size_t)(b * 2048 + tok) * 512 + h * 64 + lane] = f2b(yv - coef * vv);
}

// ---------- fused encoder: he0 -> ln1 -> he1 -> ln2 -> he2 -> rms -> proj -> z ----------
// v6 (r9/r12 verified best, 41.6us): fragment-major loads + per-XCD k-phase krot.
#define HPAD 516  // hres row stride (floats)

__device__ __forceinline__ int enc_swz(int row, int col) {
  return row * 512 + ((((col >> 3) ^ (row & 7)) << 3) | (col & 7));
}

__device__ __forceinline__ void enc_gemm(const u16* __restrict__ inb, const u16* __restrict__ Wf,
                                         floatx4* acc, int wave, int l16, int quad, int lane, int krot) {
  const u16* wb = Wf + ((size_t)(wave * 4 * 16) << 9) + lane * 8;  // ntile = wave*4+nt
  short8 aB[4];
  short8 bB[4][4];
#pragma unroll
  for (int p = 0; p < 4; p++) {
    const int kc = (p + krot) & 15;
    aB[p] = *(const short8*)(inb + enc_swz(l16, kc * 32 + quad * 8));
#pragma unroll
    for (int nt = 0; nt < 4; nt++)
      bB[p][nt] = *(const short8*)(wb + (((nt * 16) + kc) << 9));
  }
#pragma unroll
  for (int ks = 0; ks < 16; ks++) {
    const int cur = ks & 3;
#pragma unroll
    for (int nt = 0; nt < 4; nt++)
      acc[nt] = __builtin_amdgcn_mfma_f32_16x16x32_bf16(aB[cur], bB[cur][nt], acc[nt], 0, 0, 0);
    if (ks + 4 < 16) {
      const int kn = (ks + 4 + krot) & 15;
      aB[cur] = *(const short8*)(inb + enc_swz(l16, kn * 32 + quad * 8));
#pragma unroll
      for (int nt = 0; nt < 4; nt++)
        bB[cur][nt] = *(const short8*)(wb + (((nt * 16) + kn) << 9));
    }
  }
}

__global__ __launch_bounds__(512) void enc_fused(const float* __restrict__ H, const u16* __restrict__ W0b,
                                                 const u16* __restrict__ W1b, const u16* __restrict__ W2b,
                                                 const float* __restrict__ g1v, const float* __restrict__ b1v,
                                                 const float* __restrict__ g2v, const float* __restrict__ b2v,
                                                 const float* __restrict__ wout, const float* __restrict__ ct,
                                                 float* __restrict__ z) {
  __shared__ u16 curb[16 * 512];
  __shared__ u16 lnb[16 * 512];
  __shared__ float hres[16][HPAD];
  __shared__ float red[8][16][2];

  const int tid = threadIdx.x;
  const int wave = tid >> 6, lane = tid & 63, quad = lane >> 4, l16 = lane & 15;
  const int row0 = blockIdx.x * 16;
  const int n0 = wave * 64;
  const int krot = (blockIdx.x >> 3) & 15;

#pragma unroll
  for (int j = 0; j < 4; j++) {
    int idx = j * 512 + tid;
    int row = idx >> 7, c4 = idx & 127;
    float4 v = ((const float4*)H)[(size_t)(row0 + row) * 128 + c4];
    *(float4*)&hres[row][c4 * 4] = v;
    int col = c4 * 4;
    curb[enc_swz(row, col + 0)] = f2b(v.x);
    curb[enc_swz(row, col + 1)] = f2b(v.y);
    curb[enc_swz(row, col + 2)] = f2b(v.z);
    curb[enc_swz(row, col + 3)] = f2b(v.w);
  }
  __syncthreads();

  floatx4 acc1[4] = {};
  enc_gemm(curb, W0b, acc1, wave, l16, quad, lane, krot);

  {
#pragma unroll
    for (int r = 0; r < 4; r++) {
      float s = 0.f, q = 0.f;
#pragma unroll
      for (int nt = 0; nt < 4; nt++) { float v = acc1[nt][r]; s += v; q = fmaf(v, v, q); }
#pragma unroll
      for (int mk = 1; mk < 16; mk <<= 1) { s += __shfl_xor(s, mk, 64); q += __shfl_xor(q, mk, 64); }
      if (l16 == 0) { red[wave][quad * 4 + r][0] = s; red[wave][quad * 4 + r][1] = q; }
    }
    __syncthreads();
#pragma unroll
    for (int r = 0; r < 4; r++) {
      int R = quad * 4 + r;
      float st = 0.f, qt2 = 0.f;
#pragma unroll
      for (int w2 = 0; w2 < 8; w2++) { st += red[w2][R][0]; qt2 += red[w2][R][1]; }
      float mean = st * (1.f / 512.f);
      float inv = rsqrtf(qt2 * (1.f / 512.f) - mean * mean + 1e-5f);
#pragma unroll
      for (int nt = 0; nt < 4; nt++) {
        int col = n0 + nt * 16 + l16;
        lnb[enc_swz(R, col)] = f2b((acc1[nt][r] - mean) * inv * g1v[col] + b1v[col]);
      }
    }
    __syncthreads();
  }

  floatx4 acc2[4] = {};
  enc_gemm(lnb, W1b, acc2, wave, l16, quad, lane, krot);
  float hval[4][4];
  {
#pragma unroll
    for (int r = 0; r < 4; r++) {
      int R = quad * 4 + r;
      float s = 0.f, q = 0.f;
#pragma unroll
      for (int nt = 0; nt < 4; nt++) {
        int col = n0 + nt * 16 + l16;
        float u = acc2[nt][r];
        float hv = hres[R][col] + u / (1.f + __expf(-u));
        hres[R][col] = hv;
        hval[nt][r] = hv;
        s += hv; q = fmaf(hv, hv, q);
      }
#pragma unroll
      for (int mk = 1; mk < 16; mk <<= 1) { s += __shfl_xor(s, mk, 64); q += __shfl_xor(q, mk, 64); }
      if (l16 == 0) { red[wave][R][0] = s; red[wave][R][1] = q; }
    }
    __syncthreads();
#pragma unroll
    for (int r = 0; r < 4; r++) {
      int R = quad * 4 + r;
      float st = 0.f, qt2 = 0.f;
#pragma unroll
      for (int w2 = 0; w2 < 8; w2++) { st += red[w2][R][0]; qt2 += red[w2][R][1]; }
      float mean = st * (1.f / 512.f);
      float inv = rsqrtf(qt2 * (1.f / 512.f) - mean * mean + 1e-5f);
#pragma unroll
      for (int nt = 0; nt < 4; nt++) {
        int col = n0 + nt * 16 + l16;
        lnb[enc_swz(R, col)] = f2b((hval[nt][r] - mean) * inv * g2v[col] + b2v[col]);
      }
    }
    __syncthreads();
  }

  floatx4 acc3[4] = {};
  enc_gemm(lnb, W2b, acc3, wave, l16, quad, lane, krot);
  {
#pragma unroll
    for (int r = 0; r < 4; r++) {
      int R = quad * 4 + r;
      float q = 0.f;
#pragma unroll
      for (int nt = 0; nt < 4; nt++) {
        int col = n0 + nt * 16 + l16;
        float u = acc3[nt][r];
        float hv = hres[R][col] + u / (1.f + __expf(-u));
        hres[R][col] = hv;
        q = fmaf(hv, hv, q);
      }
#pragma unroll
      for (int mk = 1; mk < 16; mk <<= 1) q += __shfl_xor(q, mk, 64);
      if (l16 == 0) red[wave][R][1] = q;
    }
    __syncthreads();
  }

  {
    const int n = lane & 31, kh = lane >> 5;
    float rinv[2], pacc[2] = {0.f, 0.f};
#pragma unroll
    for (int rr = 0; rr < 2; rr++) {
      int R = wave * 2 + rr;
      float qt2 = 0.f;
#pragma unroll
      for (int w2 = 0; w2 < 8; w2++) qt2 += red[w2][R][1];
      rinv[rr] = rsqrtf(qt2 * (1.f / 512.f) + 1e-6f);
    }
    for (int kc = 0; kc < 64; kc++) {
      int k = kh * 256 + kc * 4;
      float4 wv = *(const float4*)(wout + (size_t)n * 512 + k);
#pragma unroll
      for (int rr = 0; rr < 2; rr++) {
        float4 hv = *(const float4*)&hres[wave * 2 + rr][k];
        pacc[rr] = fmaf(wv.x, hv.x, fmaf(wv.y, hv.y, fmaf(wv.z, hv.z, fmaf(wv.w, hv.w, pacc[rr]))));
      }
    }
#pragma unroll
    for (int rr = 0; rr < 2; rr++) pacc[rr] += __shfl_xor(pacc[rr], 32, 64);
    if (kh == 0) {
      float c = ct[n];
      float sp = (c > 20.f) ? c : log1pf(__expf(c));
#pragma unroll
      for (int rr = 0; rr < 2; rr++)
        z[(size_t)(row0 + wave * 2 + rr) * 32 + n] = tanhf(pacc[rr] * rinv[rr] / (sp + 1e-4f));
    }
  }
}

extern "C" void kernel_launch(void* const* d_in, const int* in_sizes, int n_in,
                              void* d_out, int out_size, void* d_ws, size_t ws_size,
                              hipStream_t stream) {
  const float* x = (const float*)d_in[0];
  const float* qp = (const float*)d_in[1];
  const float* kp = (const float*)d_in[2];
  const float* wv = (const float*)d_in[3];
  const float* wpr = (const float*)d_in[4];
  const float* qg = (const float*)d_in[5];
  const float* w0 = (const float*)d_in[6];
  const float* g1 = (const float*)d_in[7];
  const float* b1 = (const float*)d_in[8];
  const float* w1 = (const float*)d_in[9];
  const float* g2 = (const float*)d_in[10];
  const float* b2 = (const float*)d_in[11];
  const float* w2 = (const float*)d_in[12];
  const float* wout = (const float*)d_in[13];
  const float* ct = (const float*)d_in[14];
  float* z = (float*)d_out;

  float* ws = (float*)d_ws;
  const size_t MEG = 1024 * 1024;
  float* A_V = ws;                            // [0..2M floats) fp32 V (b,t,8,64) = 8MB
  u16* A_Qb = (u16*)(ws + 4 * MEG);           // [4M..4.5M)
  u16* A_Kb = (u16*)(ws + 4 * MEG + 524288);  // [4.5M..5M)
  u16* A_Vt = (u16*)(ws + 5 * MEG);           // [5M..6M)
  float* A_PO = ws + 6 * MEG;                 // [6M..10M): split-K partial O (4M floats)
  u16* A_Y2b = (u16*)(ws + 10 * MEG);         // [10M..11M)
  float* A_H = ws + 11 * MEG;                 // [11M..13M) fp32 h (4096x512)
  u16* XB = (u16*)(ws + 13 * MEG);            // [13M..14M)
  float* A_PL = ws + 13 * MEG;                // PL after XB dead (post-QKV gemm)
  u16* WCATb = (u16*)(ws + 14 * MEG);         // [14M..14.25M)
  u16* WPRb = WCATb + 524288;
  u16* W0b = WPRb + 262144;
  u16* W1b = W0b + 262144;
  u16* W2b = W1b + 262144;

  hipLaunchKernelGGL(prep_cast, dim3(5120), dim3(256), 0, stream, x, wpr, w0, w1, w2, qp, kp, wv,
                     XB, WPRb, W0b, W1b, W2b, WCATb);
  // QKV gemm + fused RoPE / V-transpose (replaces mgemm<0> + prep_attn)
  hipLaunchKernelGGL(qkv_gemm, dim3(16, 64), dim3(256), 0, stream, XB, WCATb, qg,
                     A_Qb, A_Kb, A_Vt, A_V);
  hipLaunchKernelGGL(attn_split, dim3(1024), dim3(256), 0, stream, A_Qb, A_Kb, A_Vt, A_PO, A_PL);
  hipLaunchKernelGGL(attn_combine, dim3(8192), dim3(256), 0, stream, A_PO, A_PL, A_V, A_Y2b);
  // h = y2 @ wpr^T + x   (fp32 only; enc_fused casts in-kernel)
  hipLaunchKernelGGL((mgemm<1, false>), dim3(8, 64), dim3(256), 0, stream, A_Y2b, WPRb, x, A_H,
                     (u16*)nullptr, 512);
  // fused encoder chain + final head
  hipLaunchKernelGGL(enc_fused, dim3(256), dim3(512), 0, stream, A_H, W0b, W1b, W2b,
                     g1, b1, g2, b2, wout, ct, z);
}

// Round 15
// 174.348 us; speedup vs baseline: 1.0797x; 1.0380x over previous
//
#include <hip/hip_runtime.h>
#include <math.h>

typedef unsigned short u16;
typedef __attribute__((ext_vector_type(8))) short short8;
typedef __attribute__((ext_vector_type(4))) float floatx4;

__device__ __forceinline__ float b2f(u16 u) { return __uint_as_float(((unsigned)u) << 16); }
__device__ __forceinline__ u16 f2b(float f) {
  unsigned u = __float_as_uint(f);
  return (u16)((u + 0x7fffu + ((u >> 16) & 1u)) >> 16);
}

// ---------- fused prep: cast x -> bf16 | cast 4 weights | build Wcat ----------
__global__ __launch_bounds__(256) void prep_cast(const float* __restrict__ x, const float* __restrict__ wpr,
                                                 const float* __restrict__ w0, const float* __restrict__ w1,
                                                 const float* __restrict__ w2, const float* __restrict__ qp,
                                                 const float* __restrict__ kp, const float* __restrict__ wv,
                                                 u16* __restrict__ XB, u16* __restrict__ WPRb,
                                                 u16* __restrict__ W0b, u16* __restrict__ W1b,
                                                 u16* __restrict__ W2b, u16* __restrict__ wcat) {
  int bi = blockIdx.x, tid = threadIdx.x;
  if (bi < 2048) {                       // cast_x: 524288 float4s
    int i = bi * 256 + tid;
    float4 v = ((const float4*)x)[i];
    ushort4 o; o.x = f2b(v.x); o.y = f2b(v.y); o.z = f2b(v.z); o.w = f2b(v.w);
    ((ushort4*)XB)[i] = o;
  } else if (bi < 3072) {                // cast 4x 512x512 weights: 262144 float4s
    int i = (bi - 2048) * 256 + tid;
    int sel = i >> 16, j = i & 65535;
    const float* s = sel == 0 ? wpr : sel == 1 ? w0 : sel == 2 ? w1 : w2;
    float4 v = ((const float4*)s)[j];
    ushort4 o; o.x = f2b(v.x); o.y = f2b(v.y); o.z = f2b(v.z); o.w = f2b(v.w);
    if (sel == 0) {
      ((ushort4*)WPRb)[j] = o;           // row-major (mgemm path)
    } else {                             // fragment-major scatter (enc_fused path)
      u16* d = sel == 1 ? W0b : sel == 2 ? W1b : W2b;
      int n = j >> 7, k4 = (j & 127) << 2;        // n row, k col (aligned 4)
      int lane = (((k4 >> 3) & 3) << 4) | (n & 15);
      int dst = (((n >> 4) * 16 + (k4 >> 5)) << 9) + lane * 8 + (k4 & 7);
      *(ushort4*)(d + dst) = o;
    }
  } else {                               // build_wcat: 524288 elements
    int i = (bi - 3072) * 256 + tid;
    int d = i & 511, c = i >> 9;
    float v;
    if (c < 512) {
      int hh = c >> 5, o = c & 31;
      const float* src = (hh < 8) ? qp : kp;
      int h = hh & 7;
      v = src[(h * 512 + d) * 32 + o];
    } else {
      v = wv[(c - 512) * 512 + d];
    }
    wcat[i] = f2b(v);
  }
}

// ---------- bf16 MFMA GEMM v2: BK=64, register prefetch ----------
// C[M x N] = A[M x 512] @ B^T.  EPI: 0 plain, 1 +X, 2 X + silu(acc). DUAL: also store bf16.
template <int EPI, bool DUAL>
__global__ __launch_bounds__(256) void mgemm(const u16* __restrict__ A, const u16* __restrict__ Bw,
                                             const float* __restrict__ X, float* __restrict__ C,
                                             u16* __restrict__ Cb, int N) {
  __shared__ u16 As[64][72];  // stride 144B = 9*16 (b128-aligned), banks 2-way max
  __shared__ u16 Bs[64][72];
  const int tid = threadIdx.x;
  const int bm = blockIdx.y, bn = blockIdx.x;
  const int lane = tid & 63, wave = tid >> 6;
  const int wm = wave >> 1, wn = wave & 1;
  const int quad = lane >> 4, l16 = lane & 15;
  const int sr = tid >> 2;        // staging row 0..63
  const int sk = (tid & 3) << 4;  // k-chunk 0,16,32,48
  floatx4 acc[2][2] = {};
  const u16* Ap = A + (size_t)(bm * 64 + sr) * 512 + sk;
  const u16* Bp = Bw + (size_t)(bn * 64 + sr) * 512 + sk;
  uint4 a0 = *(const uint4*)(Ap);
  uint4 a1 = *(const uint4*)(Ap + 8);
  uint4 b0 = *(const uint4*)(Bp);
  uint4 b1 = *(const uint4*)(Bp + 8);
  for (int k0 = 0; k0 < 512; k0 += 64) {
    __syncthreads();
    *(uint4*)&As[sr][sk] = a0;
    *(uint4*)&As[sr][sk + 8] = a1;
    *(uint4*)&Bs[sr][sk] = b0;
    *(uint4*)&Bs[sr][sk + 8] = b1;
    __syncthreads();
    if (k0 + 64 < 512) {  // prefetch next tile; latency overlaps MFMAs below
      a0 = *(const uint4*)(Ap + k0 + 64);
      a1 = *(const uint4*)(Ap + k0 + 72);
      b0 = *(const uint4*)(Bp + k0 + 64);
      b1 = *(const uint4*)(Bp + k0 + 72);
    }
#pragma unroll
    for (int kk = 0; kk < 2; kk++) {
      short8 af0 = *(const short8*)&As[wm * 32 + l16][kk * 32 + quad * 8];
      short8 af1 = *(const short8*)&As[wm * 32 + 16 + l16][kk * 32 + quad * 8];
      short8 bf0 = *(const short8*)&Bs[wn * 32 + l16][kk * 32 + quad * 8];
      short8 bf1 = *(const short8*)&Bs[wn * 32 + 16 + l16][kk * 32 + quad * 8];
      acc[0][0] = __builtin_amdgcn_mfma_f32_16x16x32_bf16(af0, bf0, acc[0][0], 0, 0, 0);
      acc[0][1] = __builtin_amdgcn_mfma_f32_16x16x32_bf16(af0, bf1, acc[0][1], 0, 0, 0);
      acc[1][0] = __builtin_amdgcn_mfma_f32_16x16x32_bf16(af1, bf0, acc[1][0], 0, 0, 0);
      acc[1][1] = __builtin_amdgcn_mfma_f32_16x16x32_bf16(af1, bf1, acc[1][1], 0, 0, 0);
    }
  }
#pragma unroll
  for (int mt = 0; mt < 2; mt++)
#pragma unroll
    for (int r = 0; r < 4; r++) {
      int row = bm * 64 + wm * 32 + mt * 16 + quad * 4 + r;
#pragma unroll
      for (int nt = 0; nt < 2; nt++) {
        int col = bn * 64 + wn * 32 + nt * 16 + l16;
        float v = acc[mt][nt][r];
        if (EPI == 1) {
          v += X[(size_t)row * 512 + col];
        } else if (EPI == 2) {
          float xv = X[(size_t)row * 512 + col];
          v = xv + v / (1.f + __expf(-v));
        }
        C[(size_t)row * N + col] = v;
        if (DUAL) Cb[(size_t)row * N + col] = f2b(v);
      }
    }
}

// ---------- QKV GEMM with fused RoPE epilogue + V transpose (verified r14) ----------
__global__ __launch_bounds__(256) void qkv_gemm(const u16* __restrict__ A, const u16* __restrict__ Bw,
                                                const float* __restrict__ qgain,
                                                u16* __restrict__ Qb, u16* __restrict__ Kb,
                                                u16* __restrict__ Vt, float* __restrict__ Vf) {
  __shared__ u16 As[64][72];
  __shared__ u16 Bs[64][72];
  const int tid = threadIdx.x;
  const int bm = blockIdx.y, bn = blockIdx.x;
  const int lane = tid & 63, wave = tid >> 6;
  const int wm = wave >> 1, wn = wave & 1;
  const int quad = lane >> 4, l16 = lane & 15;
  const int sr = tid >> 2;
  const int sk = (tid & 3) << 4;
  floatx4 acc[2][2] = {};
  const u16* Ap = A + (size_t)(bm * 64 + sr) * 512 + sk;
  const u16* Bp = Bw + (size_t)(bn * 64 + sr) * 512 + sk;
  uint4 a0 = *(const uint4*)(Ap);
  uint4 a1 = *(const uint4*)(Ap + 8);
  uint4 b0 = *(const uint4*)(Bp);
  uint4 b1 = *(const uint4*)(Bp + 8);
  for (int k0 = 0; k0 < 512; k0 += 64) {
    __syncthreads();
    *(uint4*)&As[sr][sk] = a0;
    *(uint4*)&As[sr][sk + 8] = a1;
    *(uint4*)&Bs[sr][sk] = b0;
    *(uint4*)&Bs[sr][sk + 8] = b1;
    __syncthreads();
    if (k0 + 64 < 512) {
      a0 = *(const uint4*)(Ap + k0 + 64);
      a1 = *(const uint4*)(Ap + k0 + 72);
      b0 = *(const uint4*)(Bp + k0 + 64);
      b1 = *(const uint4*)(Bp + k0 + 72);
    }
#pragma unroll
    for (int kk = 0; kk < 2; kk++) {
      short8 af0 = *(const short8*)&As[wm * 32 + l16][kk * 32 + quad * 8];
      short8 af1 = *(const short8*)&As[wm * 32 + 16 + l16][kk * 32 + quad * 8];
      short8 bf0 = *(const short8*)&Bs[wn * 32 + l16][kk * 32 + quad * 8];
      short8 bf1 = *(const short8*)&Bs[wn * 32 + 16 + l16][kk * 32 + quad * 8];
      acc[0][0] = __builtin_amdgcn_mfma_f32_16x16x32_bf16(af0, bf0, acc[0][0], 0, 0, 0);
      acc[0][1] = __builtin_amdgcn_mfma_f32_16x16x32_bf16(af0, bf1, acc[0][1], 0, 0, 0);
      acc[1][0] = __builtin_amdgcn_mfma_f32_16x16x32_bf16(af1, bf0, acc[1][0], 0, 0, 0);
      acc[1][1] = __builtin_amdgcn_mfma_f32_16x16x32_bf16(af1, bf1, acc[1][1], 0, 0, 0);
    }
  }
  if (bn < 8) {
    // ---- q/k RoPE epilogue ----
    const bool isq = (bn < 4);
    const int h = (isq ? bn : bn - 4) * 2 + wn;
    // gain * 1/sqrt(32) * log2(e) for q (exp2 softmax downstream); k raw
    const float gq = isq ? qgain[h] * (0.17677669529663687f * 1.4426950408889634f) : 1.f;
    const float freq = powf(10000.f, -(float)l16 / 16.f);
    u16* outb = (isq ? Qb : Kb);
#pragma unroll
    for (int mt = 0; mt < 2; mt++)
#pragma unroll
      for (int r = 0; r < 4; r++) {
        int row = bm * 64 + wm * 32 + mt * 16 + quad * 4 + r;
        int t = row & 2047, b = row >> 11;
        float s, c;
        sincosf((float)t * freq, &s, &c);
        float q0 = acc[mt][0][r], q1 = acc[mt][1][r];
        u16* base = outb + ((size_t)((b * 8 + h) * 2048 + t)) * 32;
        if (isq) {
          base[l16] = f2b((q0 * c - q1 * s) * gq);
          base[l16 + 16] = f2b((q1 * c + q0 * s) * gq);
        } else {
          base[l16] = f2b(q0 * c - q1 * s);
          base[l16 + 16] = f2b(q1 * c + q0 * s);
        }
      }
  } else {
    // ---- v epilogue: fp32 store + bf16 transpose ----
    const int h = bn - 8;
    const int b = bm >> 5;  // 64 rows per block, 2048 rows per batch
#pragma unroll
    for (int mt = 0; mt < 2; mt++)
#pragma unroll
      for (int r = 0; r < 4; r++) {
        int row = bm * 64 + wm * 32 + mt * 16 + quad * 4 + r;
#pragma unroll
        for (int nt = 0; nt < 2; nt++) {
          int d = wn * 32 + nt * 16 + l16;
          Vf[(size_t)row * 512 + h * 64 + d] = acc[mt][nt][r];
        }
      }
    __syncthreads();  // all waves done reading As/Bs in K-loop
#pragma unroll
    for (int mt = 0; mt < 2; mt++)
#pragma unroll
      for (int r = 0; r < 4; r++) {
        int rl = wm * 32 + mt * 16 + quad * 4 + r;
#pragma unroll
        for (int nt = 0; nt < 2; nt++) {
          int d = wn * 32 + nt * 16 + l16;
          As[d][rl] = f2b(acc[mt][nt][r]);
        }
      }
    __syncthreads();
    const int bh = b * 8 + h;
    const int t0 = (bm & 31) * 64;  // t within batch
    const int dim = tid >> 2, ch = (tid & 3) << 4;
    u16* dst = Vt + ((size_t)(bh * 64 + dim)) * 2048 + t0 + ch;
    *(uint4*)dst = *(const uint4*)&As[dim][ch];
    *(uint4*)(dst + 8) = *(const uint4*)&As[dim][ch + 8];
  }
}

// ---------- MFMA causal attention, NO split-K, fused normalize + self-align ----------
// 512 blocks; blocks j and j+256 have qt and 31-qt (same CU under round-robin
// dispatch: 256=0 mod 8 XCDs, offset 32=0 mod 32 CUs) -> per-CU work = 33 iters.
// Each block owns its full O row: normalize by own l, self-align in-register
// (d = nt*16+l16: nt-sum in-thread + 16-lane shfl reduce), write y2b directly.
// Replaces attn_split + attn_combine; kills 16MB PO wr + 16MB rd + PL + a launch.
__global__ __launch_bounds__(256) void attn_fused(const u16* __restrict__ Qb, const u16* __restrict__ Kb,
                                                  const u16* __restrict__ Vt, const float* __restrict__ Vf,
                                                  u16* __restrict__ y2b) {
  const int bi = blockIdx.x;               // 512 blocks
  const int bh = bi & 15;
  const int q0i = (bi >> 4) & 15;
  const int hi = bi >> 8;
  const int qt = hi ? (31 - q0i) : q0i;
  const int tid = threadIdx.x;
  const int w = tid >> 6, lane = tid & 63, quad = lane >> 4, l16 = lane & 15;
  __shared__ u16 Vts[64][72];
  __shared__ u16 Ps[4][16][72];

  short8 qfrag = *(const short8*)(Qb + ((size_t)(bh * 2048 + qt * 64 + w * 16 + l16)) * 32 + quad * 8);
  floatx4 o_acc[4] = {};
  float l_part[4] = {0.f, 0.f, 0.f, 0.f};
  const u16* Kbase = Kb + (size_t)bh * 2048 * 32;
  const u16* Vtb = Vt + (size_t)bh * 64 * 2048;
  const int vr = tid >> 2, vc = (tid & 3) << 4;

  uint4 v0, v1;
  short8 kf[4];
  {
    const u16* src = Vtb + (size_t)vr * 2048 + vc;
    v0 = *(const uint4*)src;
    v1 = *(const uint4*)(src + 8);
#pragma unroll
    for (int nt = 0; nt < 4; nt++)
      kf[nt] = *(const short8*)(Kbase + (size_t)(nt * 16 + l16) * 32 + quad * 8);
  }

  for (int kt = 0; kt <= qt; ++kt) {
    __syncthreads();
    *(uint4*)&Vts[vr][vc] = v0;
    *(uint4*)&Vts[vr][vc + 8] = v1;
    __syncthreads();
    const bool more = (kt < qt);
    uint4 v0n = {}, v1n = {};
    short8 kfn[4] = {};
    if (more) {  // prefetch next K/V; latency overlaps exp+MFMA below
      const u16* src = Vtb + (size_t)vr * 2048 + (kt + 1) * 64 + vc;
      v0n = *(const uint4*)src;
      v1n = *(const uint4*)(src + 8);
#pragma unroll
      for (int nt = 0; nt < 4; nt++)
        kfn[nt] = *(const short8*)(Kbase + (size_t)((kt + 1) * 64 + nt * 16 + l16) * 32 + quad * 8);
    }

    floatx4 s_acc[4];
    __builtin_amdgcn_s_setprio(1);
#pragma unroll
    for (int nt = 0; nt < 4; nt++) {
      floatx4 zz = {0.f, 0.f, 0.f, 0.f};
      s_acc[nt] = __builtin_amdgcn_mfma_f32_16x16x32_bf16(qfrag, kf[nt], zz, 0, 0, 0);
    }
    __builtin_amdgcn_s_setprio(0);
    const bool diag = (kt == qt);
#pragma unroll
    for (int r = 0; r < 4; r++) {
      int mloc = w * 16 + quad * 4 + r;
      float psum = 0.f;
#pragma unroll
      for (int nt = 0; nt < 4; nt++) {
        float p = __builtin_amdgcn_exp2f(s_acc[nt][r]);  // log2e folded into q-gain
        if (diag && (nt * 16 + l16) > mloc) p = 0.f;
        psum += p;
        Ps[w][quad * 4 + r][nt * 16 + l16] = f2b(p);
      }
      l_part[r] += psum;
    }
    __builtin_amdgcn_s_setprio(1);
#pragma unroll
    for (int kc = 0; kc < 2; kc++) {
      short8 pf = *(const short8*)&Ps[w][l16][kc * 32 + quad * 8];
#pragma unroll
      for (int nt = 0; nt < 4; nt++) {
        short8 vf = *(const short8*)&Vts[nt * 16 + l16][kc * 32 + quad * 8];
        o_acc[nt] = __builtin_amdgcn_mfma_f32_16x16x32_bf16(pf, vf, o_acc[nt], 0, 0, 0);
      }
    }
    __builtin_amdgcn_s_setprio(0);
    v0 = v0n; v1 = v1n;
#pragma unroll
    for (int nt = 0; nt < 4; nt++) kf[nt] = kfn[nt];
  }

  // ---- fused epilogue: normalize + self-align + store ----
  const int b = bh >> 3, h = bh & 7;
#pragma unroll
  for (int r = 0; r < 4; r++) {
    float ls = l_part[r];
#pragma unroll
    for (int mk = 1; mk < 16; mk <<= 1) ls += __shfl_xor(ls, mk, 64);
    int tok = qt * 64 + w * 16 + quad * 4 + r;
    float linv = 1.f / ls;
    const float* vp = Vf + (size_t)(b * 2048 + tok) * 512 + h * 64 + l16;
    float yv[4], vv[4];
    float dot = 0.f, ss = 0.f;
#pragma unroll
    for (int nt = 0; nt < 4; nt++) {
      yv[nt] = o_acc[nt][r] * linv;
      vv[nt] = vp[nt * 16];
      dot = fmaf(yv[nt], vv[nt], dot);
      ss = fmaf(vv[nt], vv[nt], ss);
    }
#pragma unroll
    for (int mk = 1; mk < 16; mk <<= 1) {
      dot += __shfl_xor(dot, mk, 64);
      ss += __shfl_xor(ss, mk, 64);
    }
    float coef = dot / fmaxf(ss, 1e-24f);
    u16* op = y2b + (size_t)(b * 2048 + tok) * 512 + h * 64 + l16;
#pragma unroll
    for (int nt = 0; nt < 4; nt++) op[nt * 16] = f2b(yv[nt] - coef * vv[nt]);
  }
}

// ---------- fused encoder: he0 -> ln1 -> he1 -> ln2 -> he2 -> rms -> proj -> z ----------
// v6 (r9/r12 verified best, 41.6us): fragment-major loads + per-XCD k-phase krot.
#define HPAD 516  // hres row stride (floats)

__device__ __forceinline__ int enc_swz(int row, int col) {
  return row * 512 + ((((col >> 3) ^ (row & 7)) << 3) | (col & 7));
}

__device__ __forceinline__ void enc_gemm(const u16* __restrict__ inb, const u16* __restrict__ Wf,
                                         floatx4* acc, int wave, int l16, int quad, int lane, int krot) {
  const u16* wb = Wf + ((size_t)(wave * 4 * 16) << 9) + lane * 8;  // ntile = wave*4+nt
  short8 aB[4];
  short8 bB[4][4];
#pragma unroll
  for (int p = 0; p < 4; p++) {
    const int kc = (p + krot) & 15;
    aB[p] = *(const short8*)(inb + enc_swz(l16, kc * 32 + quad * 8));
#pragma unroll
    for (int nt = 0; nt < 4; nt++)
      bB[p][nt] = *(const short8*)(wb + (((nt * 16) + kc) << 9));
  }
#pragma unroll
  for (int ks = 0; ks < 16; ks++) {
    const int cur = ks & 3;
#pragma unroll
    for (int nt = 0; nt < 4; nt++)
      acc[nt] = __builtin_amdgcn_mfma_f32_16x16x32_bf16(aB[cur], bB[cur][nt], acc[nt], 0, 0, 0);
    if (ks + 4 < 16) {
      const int kn = (ks + 4 + krot) & 15;
      aB[cur] = *(const short8*)(inb + enc_swz(l16, kn * 32 + quad * 8));
#pragma unroll
      for (int nt = 0; nt < 4; nt++)
        bB[cur][nt] = *(const short8*)(wb + (((nt * 16) + kn) << 9));
    }
  }
}

__global__ __launch_bounds__(512) void enc_fused(const float* __restrict__ H, const u16* __restrict__ W0b,
                                                 const u16* __restrict__ W1b, const u16* __restrict__ W2b,
                                                 const float* __restrict__ g1v, const float* __restrict__ b1v,
                                                 const float* __restrict__ g2v, const float* __restrict__ b2v,
                                                 const float* __restrict__ wout, const float* __restrict__ ct,
                                                 float* __restrict__ z) {
  __shared__ u16 curb[16 * 512];
  __shared__ u16 lnb[16 * 512];
  __shared__ float hres[16][HPAD];
  __shared__ float red[8][16][2];

  const int tid = threadIdx.x;
  const int wave = tid >> 6, lane = tid & 63, quad = lane >> 4, l16 = lane & 15;
  const int row0 = blockIdx.x * 16;
  const int n0 = wave * 64;
  const int krot = (blockIdx.x >> 3) & 15;

#pragma unroll
  for (int j = 0; j < 4; j++) {
    int idx = j * 512 + tid;
    int row = idx >> 7, c4 = idx & 127;
    float4 v = ((const float4*)H)[(size_t)(row0 + row) * 128 + c4];
    *(float4*)&hres[row][c4 * 4] = v;
    int col = c4 * 4;
    curb[enc_swz(row, col + 0)] = f2b(v.x);
    curb[enc_swz(row, col + 1)] = f2b(v.y);
    curb[enc_swz(row, col + 2)] = f2b(v.z);
    curb[enc_swz(row, col + 3)] = f2b(v.w);
  }
  __syncthreads();

  floatx4 acc1[4] = {};
  enc_gemm(curb, W0b, acc1, wave, l16, quad, lane, krot);

  {
#pragma unroll
    for (int r = 0; r < 4; r++) {
      float s = 0.f, q = 0.f;
#pragma unroll
      for (int nt = 0; nt < 4; nt++) { float v = acc1[nt][r]; s += v; q = fmaf(v, v, q); }
#pragma unroll
      for (int mk = 1; mk < 16; mk <<= 1) { s += __shfl_xor(s, mk, 64); q += __shfl_xor(q, mk, 64); }
      if (l16 == 0) { red[wave][quad * 4 + r][0] = s; red[wave][quad * 4 + r][1] = q; }
    }
    __syncthreads();
#pragma unroll
    for (int r = 0; r < 4; r++) {
      int R = quad * 4 + r;
      float st = 0.f, qt2 = 0.f;
#pragma unroll
      for (int w2 = 0; w2 < 8; w2++) { st += red[w2][R][0]; qt2 += red[w2][R][1]; }
      float mean = st * (1.f / 512.f);
      float inv = rsqrtf(qt2 * (1.f / 512.f) - mean * mean + 1e-5f);
#pragma unroll
      for (int nt = 0; nt < 4; nt++) {
        int col = n0 + nt * 16 + l16;
        lnb[enc_swz(R, col)] = f2b((acc1[nt][r] - mean) * inv * g1v[col] + b1v[col]);
      }
    }
    __syncthreads();
  }

  floatx4 acc2[4] = {};
  enc_gemm(lnb, W1b, acc2, wave, l16, quad, lane, krot);
  float hval[4][4];
  {
#pragma unroll
    for (int r = 0; r < 4; r++) {
      int R = quad * 4 + r;
      float s = 0.f, q = 0.f;
#pragma unroll
      for (int nt = 0; nt < 4; nt++) {
        int col = n0 + nt * 16 + l16;
        float u = acc2[nt][r];
        float hv = hres[R][col] + u / (1.f + __expf(-u));
        hres[R][col] = hv;
        hval[nt][r] = hv;
        s += hv; q = fmaf(hv, hv, q);
      }
#pragma unroll
      for (int mk = 1; mk < 16; mk <<= 1) { s += __shfl_xor(s, mk, 64); q += __shfl_xor(q, mk, 64); }
      if (l16 == 0) { red[wave][R][0] = s; red[wave][R][1] = q; }
    }
    __syncthreads();
#pragma unroll
    for (int r = 0; r < 4; r++) {
      int R = quad * 4 + r;
      float st = 0.f, qt2 = 0.f;
#pragma unroll
      for (int w2 = 0; w2 < 8; w2++) { st += red[w2][R][0]; qt2 += red[w2][R][1]; }
      float mean = st * (1.f / 512.f);
      float inv = rsqrtf(qt2 * (1.f / 512.f) - mean * mean + 1e-5f);
#pragma unroll
      for (int nt = 0; nt < 4; nt++) {
        int col = n0 + nt * 16 + l16;
        lnb[enc_swz(R, col)] = f2b((hval[nt][r] - mean) * inv * g2v[col] + b2v[col]);
      }
    }
    __syncthreads();
  }

  floatx4 acc3[4] = {};
  enc_gemm(lnb, W2b, acc3, wave, l16, quad, lane, krot);
  {
#pragma unroll
    for (int r = 0; r < 4; r++) {
      int R = quad * 4 + r;
      float q = 0.f;
#pragma unroll
      for (int nt = 0; nt < 4; nt++) {
        int col = n0 + nt * 16 + l16;
        float u = acc3[nt][r];
        float hv = hres[R][col] + u / (1.f + __expf(-u));
        hres[R][col] = hv;
        q = fmaf(hv, hv, q);
      }
#pragma unroll
      for (int mk = 1; mk < 16; mk <<= 1) q += __shfl_xor(q, mk, 64);
      if (l16 == 0) red[wave][R][1] = q;
    }
    __syncthreads();
  }

  {
    const int n = lane & 31, kh = lane >> 5;
    float rinv[2], pacc[2] = {0.f, 0.f};
#pragma unroll
    for (int rr = 0; rr < 2; rr++) {
      int R = wave * 2 + rr;
      float qt2 = 0.f;
#pragma unroll
      for (int w2 = 0; w2 < 8; w2++) qt2 += red[w2][R][1];
      rinv[rr] = rsqrtf(qt2 * (1.f / 512.f) + 1e-6f);
    }
    for (int kc = 0; kc < 64; kc++) {
      int k = kh * 256 + kc * 4;
      float4 wv = *(const float4*)(wout + (size_t)n * 512 + k);
#pragma unroll
      for (int rr = 0; rr < 2; rr++) {
        float4 hv = *(const float4*)&hres[wave * 2 + rr][k];
        pacc[rr] = fmaf(wv.x, hv.x, fmaf(wv.y, hv.y, fmaf(wv.z, hv.z, fmaf(wv.w, hv.w, pacc[rr]))));
      }
    }
#pragma unroll
    for (int rr = 0; rr < 2; rr++) pacc[rr] += __shfl_xor(pacc[rr], 32, 64);
    if (kh == 0) {
      float c = ct[n];
      float sp = (c > 20.f) ? c : log1pf(__expf(c));
#pragma unroll
      for (int rr = 0; rr < 2; rr++)
        z[(size_t)(row0 + wave * 2 + rr) * 32 + n] = tanhf(pacc[rr] * rinv[rr] / (sp + 1e-4f));
    }
  }
}

extern "C" void kernel_launch(void* const* d_in, const int* in_sizes, int n_in,
                              void* d_out, int out_size, void* d_ws, size_t ws_size,
                              hipStream_t stream) {
  const float* x = (const float*)d_in[0];
  const float* qp = (const float*)d_in[1];
  const float* kp = (const float*)d_in[2];
  const float* wv = (const float*)d_in[3];
  const float* wpr = (const float*)d_in[4];
  const float* qg = (const float*)d_in[5];
  const float* w0 = (const float*)d_in[6];
  const float* g1 = (const float*)d_in[7];
  const float* b1 = (const float*)d_in[8];
  const float* w1 = (const float*)d_in[9];
  const float* g2 = (const float*)d_in[10];
  const float* b2 = (const float*)d_in[11];
  const float* w2 = (const float*)d_in[12];
  const float* wout = (const float*)d_in[13];
  const float* ct = (const float*)d_in[14];
  float* z = (float*)d_out;

  float* ws = (float*)d_ws;
  const size_t MEG = 1024 * 1024;
  float* A_V = ws;                            // [0..2M floats) fp32 V (b,t,8,64) = 8MB
  u16* A_Qb = (u16*)(ws + 4 * MEG);           // [4M..4.5M)
  u16* A_Kb = (u16*)(ws + 4 * MEG + 524288);  // [4.5M..5M)
  u16* A_Vt = (u16*)(ws + 5 * MEG);           // [5M..6M)
  u16* A_Y2b = (u16*)(ws + 10 * MEG);         // [10M..11M)
  float* A_H = ws + 11 * MEG;                 // [11M..13M) fp32 h (4096x512)
  u16* XB = (u16*)(ws + 13 * MEG);            // [13M..14M)
  u16* WCATb = (u16*)(ws + 14 * MEG);         // [14M..14.25M)
  u16* WPRb = WCATb + 524288;
  u16* W0b = WPRb + 262144;
  u16* W1b = W0b + 262144;
  u16* W2b = W1b + 262144;

  hipLaunchKernelGGL(prep_cast, dim3(5120), dim3(256), 0, stream, x, wpr, w0, w1, w2, qp, kp, wv,
                     XB, WPRb, W0b, W1b, W2b, WCATb);
  // QKV gemm + fused RoPE / V-transpose
  hipLaunchKernelGGL(qkv_gemm, dim3(16, 64), dim3(256), 0, stream, XB, WCATb, qg,
                     A_Qb, A_Kb, A_Vt, A_V);
  // attention: no split-K, fused normalize + self-align (replaces attn_split+attn_combine)
  hipLaunchKernelGGL(attn_fused, dim3(512), dim3(256), 0, stream, A_Qb, A_Kb, A_Vt, A_V, A_Y2b);
  // h = y2 @ wpr^T + x   (fp32 only; enc_fused casts in-kernel)
  hipLaunchKernelGGL((mgemm<1, false>), dim3(8, 64), dim3(256), 0, stream, A_Y2b, WPRb, x, A_H,
                     (u16*)nullptr, 512);
  // fused encoder chain + final head
  hipLaunchKernelGGL(enc_fused, dim3(256), dim3(512), 0, stream, A_H, W0b, W1b, W2b,
                     g1, b1, g2, b2, wout, ct, z);
}